// Round 1
// baseline (430.577 us; speedup 1.0000x reference)
//
#include <hip/hip_runtime.h>

// ---------------------------------------------------------------------------
// PromptSelector: only the CLS token's final vector feeds the outputs.
// Heavy path: LN1(all rows) -> K,V = LN1(x) @ [Wk|Wv] (split-bf16 MFMA GEMM)
// Light path (row 0 only, fp32): q0, attention over 1024 keys, Wo, FFN, LNs,
// pool/class heads, top-k rank, gather prompt_pool.
// ---------------------------------------------------------------------------

typedef __attribute__((ext_vector_type(8))) short bf16x8;
typedef __attribute__((ext_vector_type(4))) float f32x4;
typedef unsigned short u16;

#define NDIM 768
#define MROWS 8192      // 8 * 1024
#define NKV 1536        // K | V columns
#define NFF 3072
#define OUT_CLS_OFF 614400   // 8*100*768

__device__ __forceinline__ u16 f2bf(float f) {
    union { float f; unsigned int u; } v; v.f = f;
    unsigned int u = v.u;
    return (u16)((u + 0x7fffu + ((u >> 16) & 1u)) >> 16);   // RNE
}
__device__ __forceinline__ float bf2f(u16 h) {
    union { unsigned int u; float f; } v; v.u = ((unsigned int)h) << 16;
    return v.f;
}
__device__ __forceinline__ void gload16(const void* g, void* l) {
    __builtin_amdgcn_global_load_lds((const __attribute__((address_space(1))) void*)g,
                                     (__attribute__((address_space(3))) void*)l, 16, 0, 0);
}

// block-wide (256 thr) sum reduce; red must hold >=4 floats
__device__ __forceinline__ float bsum256(float v, float* red) {
    int lane = threadIdx.x & 63, w = threadIdx.x >> 6;
#pragma unroll
    for (int off = 1; off < 64; off <<= 1) v += __shfl_xor(v, off);
    __syncthreads();
    if (lane == 0) red[w] = v;
    __syncthreads();
    return red[0] + red[1] + red[2] + red[3];
}

// ---------------------------------------------------------------------------
// prep: transpose Wk|Wv (768 x 1536, row-major K x N) into Bt[n][k] split into
// bf16 hi/lo planes. Tiled 64x64 via LDS, all global accesses coalesced.
__global__ __launch_bounds__(256) void prep_weights(
    const float* __restrict__ Wk, const float* __restrict__ Wv,
    u16* __restrict__ Bh, u16* __restrict__ Bl)
{
    __shared__ float tile[64][65];
    int n0 = blockIdx.x * 64, k0 = blockIdx.y * 64;
    const float* src = (n0 < 768) ? Wk : Wv;
    int nc = (n0 < 768) ? n0 : (n0 - 768);
    int t = threadIdx.x;
    int cr = t >> 6, cc = t & 63;
#pragma unroll
    for (int i = 0; i < 16; ++i) {
        int kl = i * 4 + cr;
        tile[kl][cc] = src[(size_t)(k0 + kl) * 768 + nc + cc];
    }
    __syncthreads();
#pragma unroll
    for (int i = 0; i < 16; ++i) {
        int nl = i * 4 + cr;
        float w = tile[cc][nl];
        u16 h = f2bf(w);
        size_t o = (size_t)(n0 + nl) * 768 + k0 + cc;
        Bh[o] = h;
        Bl[o] = f2bf(w - bf2f(h));
    }
}

// ---------------------------------------------------------------------------
// LN1 over all 8192 rows (row = b*1024 + s; s==0 -> cls_token broadcast).
// Emits split-bf16 planes Ahi/Alo; row 0 (identical for every batch) also
// emitted in fp32 for the q-path.
__global__ __launch_bounds__(256) void ln1_split(
    const float* __restrict__ tf, const float* __restrict__ clsT,
    const float* __restrict__ ga, const float* __restrict__ gb,
    u16* __restrict__ Ahi, u16* __restrict__ Alo, float* __restrict__ y0)
{
    __shared__ float red[4];
    int row = blockIdx.x;
    int bb = row >> 10, s = row & 1023;
    const float* src = s ? (tf + ((size_t)bb * 1023 + (s - 1)) * 768) : clsT;
    int t = threadIdx.x;
    float a0 = src[t], a1 = src[t + 256], a2 = src[t + 512];
    float mean = bsum256(a0 + a1 + a2, red) / 768.0f;
    float d0 = a0 - mean, d1 = a1 - mean, d2 = a2 - mean;
    float var = bsum256(d0 * d0 + d1 * d1 + d2 * d2, red) / 767.0f;
    float den = sqrtf(var) + 1e-6f;
    float yv0 = (ga[t] * d0) / den + gb[t];
    float yv1 = (ga[t + 256] * d1) / den + gb[t + 256];
    float yv2 = (ga[t + 512] * d2) / den + gb[t + 512];
    size_t base = (size_t)row * 768;
    u16 h0 = f2bf(yv0), h1 = f2bf(yv1), h2 = f2bf(yv2);
    Ahi[base + t] = h0;        Alo[base + t] = f2bf(yv0 - bf2f(h0));
    Ahi[base + t + 256] = h1;  Alo[base + t + 256] = f2bf(yv1 - bf2f(h1));
    Ahi[base + t + 512] = h2;  Alo[base + t + 512] = f2bf(yv2 - bf2f(h2));
    if (row == 0) { y0[t] = yv0; y0[t + 256] = yv1; y0[t + 512] = yv2; }
}

// ---------------------------------------------------------------------------
// Split-bf16 GEMM: C[8192][1536] = (Ah+Al)[8192][768] @ (Bh+Bl)^T[1536][768]
// 3-term: AhBh + AhBl + AlBh. 128x128 tile, BK=32, 4 waves (2x2 of 64x64),
// global_load_lds(16B) staging, double-row XOR swizzle => conflict-free reads.
__global__ __launch_bounds__(256) void kv_gemm(
    const u16* __restrict__ Ahi, const u16* __restrict__ Alo,
    const u16* __restrict__ Bth, const u16* __restrict__ Btl,
    const float* __restrict__ bK, const float* __restrict__ bV,
    float* __restrict__ C)
{
    __shared__ u16 sAh[4096], sAl[4096], sBh[4096], sBl[4096];
    const int t = threadIdx.x;
    const int lane = t & 63, wave = t >> 6;
    const int wm = (wave >> 1) * 64, wn = (wave & 1) * 64;
    const int m0 = blockIdx.x * 128, n0 = blockIdx.y * 128;

    // staging decode: LDS linear granule t -> (row, chunk) with XOR swizzle
    const int dr0 = t >> 3;                  // 0..31 (double-row in call 0)
    const int g0 = t & 7;
    const int u0 = g0 ^ (dr0 & 7);
    const int srow = (dr0 << 1) + (u0 >> 2); // 0..63
    const int scol = (u0 & 3) << 3;          // element col 0/8/16/24
    const u16* pAh = Ahi + (size_t)(m0 + srow) * 768 + scol;
    const u16* pAl = Alo + (size_t)(m0 + srow) * 768 + scol;
    const u16* pBh = Bth + (size_t)(n0 + srow) * 768 + scol;
    const u16* pBl = Btl + (size_t)(n0 + srow) * 768 + scol;
    const int half = 64 * 768;               // +64 rows for second 4KB call

    // fragment read byte-offsets (swizzled)
    const int lm = lane & 15, chunk = lane >> 4;
    int offA[4], offB[4];
#pragma unroll
    for (int f = 0; f < 4; ++f) {
        int rm = wm + f * 16 + lm;
        int dr = rm >> 1;
        int g = (((rm & 1) << 2) + chunk) ^ (dr & 7);
        offA[f] = dr * 128 + g * 16;
        int rn = wn + f * 16 + lm;
        int dn = rn >> 1;
        int gn = (((rn & 1) << 2) + chunk) ^ (dn & 7);
        offB[f] = dn * 128 + gn * 16;
    }

    f32x4 acc[4][4] = {};
    for (int kt = 0; kt < 24; ++kt) {
        const int k0 = kt << 5;
        gload16(pAh + k0, sAh + t * 8);
        gload16(pAh + half + k0, sAh + 2048 + t * 8);
        gload16(pAl + k0, sAl + t * 8);
        gload16(pAl + half + k0, sAl + 2048 + t * 8);
        gload16(pBh + k0, sBh + t * 8);
        gload16(pBh + half + k0, sBh + 2048 + t * 8);
        gload16(pBl + k0, sBl + t * 8);
        gload16(pBl + half + k0, sBl + 2048 + t * 8);
        __syncthreads();
        bf16x8 ah[4], al[4], bh[4], bl[4];
#pragma unroll
        for (int f = 0; f < 4; ++f) {
            ah[f] = *(const bf16x8*)((const char*)sAh + offA[f]);
            al[f] = *(const bf16x8*)((const char*)sAl + offA[f]);
            bh[f] = *(const bf16x8*)((const char*)sBh + offB[f]);
            bl[f] = *(const bf16x8*)((const char*)sBl + offB[f]);
        }
#pragma unroll
        for (int i = 0; i < 4; ++i)
#pragma unroll
            for (int j = 0; j < 4; ++j) {
                acc[i][j] = __builtin_amdgcn_mfma_f32_16x16x32_bf16(ah[i], bh[j], acc[i][j], 0, 0, 0);
                acc[i][j] = __builtin_amdgcn_mfma_f32_16x16x32_bf16(ah[i], bl[j], acc[i][j], 0, 0, 0);
                acc[i][j] = __builtin_amdgcn_mfma_f32_16x16x32_bf16(al[i], bh[j], acc[i][j], 0, 0, 0);
            }
        __syncthreads();
    }

    const int colb = n0 + wn + (lane & 15);
    const int rowb = m0 + wm + ((lane >> 4) << 2);
#pragma unroll
    for (int i = 0; i < 4; ++i)
#pragma unroll
        for (int j = 0; j < 4; ++j) {
            int col = colb + j * 16;
            float bias = (col < 768) ? bK[col] : bV[col - 768];
#pragma unroll
            for (int r = 0; r < 4; ++r) {
                int row = rowb + i * 16 + r;
                C[(size_t)row * NKV + col] = acc[i][j][r] + bias;
            }
        }
}

// ---------------------------------------------------------------------------
// q0 = LN1(cls) @ Wq + bq  (single 768-vector, same for all batches)
__global__ __launch_bounds__(256) void q0_kernel(
    const float* __restrict__ y0, const float* __restrict__ Wq,
    const float* __restrict__ bq, float* __restrict__ q0)
{
    __shared__ float ys[768];
    __shared__ float prt[8][33];
    int t = threadIdx.x;
    for (int i = t; i < 768; i += 256) ys[i] = y0[i];
    __syncthreads();
    int c = blockIdx.x * 32 + (t & 31);
    int kg = t >> 5;
    float acc = 0.f;
    for (int k = kg; k < 768; k += 8) acc += ys[k] * Wq[(size_t)k * 768 + c];
    prt[kg][t & 31] = acc;
    __syncthreads();
    if (kg == 0) {
        float s = 0.f;
#pragma unroll
        for (int i = 0; i < 8; ++i) s += prt[i][t];
        q0[c] = s + bq[c];
    }
}

// ---------------------------------------------------------------------------
// Row-0 attention: one block per (b,h); 1024 threads, thread j owns key j.
__global__ __launch_bounds__(1024) void attn0_kernel(
    const float* __restrict__ kv, const float* __restrict__ q0,
    float* __restrict__ o0)
{
    __shared__ float qs[48];
    __shared__ float red[16];
    __shared__ float op[16][48];
    int blk = blockIdx.x;
    int bb = blk >> 4, h = blk & 15;
    int t = threadIdx.x;
    int lane = t & 63, w = t >> 6;
    if (t < 48) qs[t] = q0[h * 48 + t];
    __syncthreads();

    const float* krow = kv + ((size_t)(bb << 10) + t) * NKV + h * 48;
    const float4* k4p = (const float4*)krow;
    float s = 0.f;
#pragma unroll
    for (int i = 0; i < 12; ++i) {
        float4 k4 = k4p[i];
        s += qs[4 * i] * k4.x + qs[4 * i + 1] * k4.y + qs[4 * i + 2] * k4.z + qs[4 * i + 3] * k4.w;
    }
    s = s / sqrtf(48.0f);

    float m = s;
#pragma unroll
    for (int off = 1; off < 64; off <<= 1) m = fmaxf(m, __shfl_xor(m, off));
    if (lane == 0) red[w] = m;
    __syncthreads();
    float mm = red[0];
#pragma unroll
    for (int i = 1; i < 16; ++i) mm = fmaxf(mm, red[i]);
    float p = expf(s - mm);
    float z = p;
#pragma unroll
    for (int off = 1; off < 64; off <<= 1) z += __shfl_xor(z, off);
    __syncthreads();
    if (lane == 0) red[w] = z;
    __syncthreads();
    float zz = 0.f;
#pragma unroll
    for (int i = 0; i < 16; ++i) zz += red[i];
    p = p / zz;

    float vr[48];
    const float4* v4p = (const float4*)(krow + 768);
#pragma unroll
    for (int i = 0; i < 12; ++i) {
        float4 v4 = v4p[i];
        vr[4 * i] = v4.x; vr[4 * i + 1] = v4.y; vr[4 * i + 2] = v4.z; vr[4 * i + 3] = v4.w;
    }
#pragma unroll
    for (int d = 0; d < 48; ++d) {
        float val = p * vr[d];
#pragma unroll
        for (int off = 1; off < 64; off <<= 1) val += __shfl_xor(val, off);
        if (lane == 0) op[w][d] = val;
    }
    __syncthreads();
    if (t < 48) {
        float acc = 0.f;
#pragma unroll
        for (int i = 0; i < 16; ++i) acc += op[i][t];
        o0[bb * 768 + h * 48 + t] = acc;
    }
}

// ---------------------------------------------------------------------------
// Small row GEMMs for the 8 CLS rows, spread over many blocks (per-CU BW).
// grid (24, 8): 32 cols per block; x2 = cls_token + o0 @ Wo + bo
__global__ __launch_bounds__(256) void t1_x2(
    const float* __restrict__ o0, const float* __restrict__ Wo,
    const float* __restrict__ bo, const float* __restrict__ clsT,
    float* __restrict__ x2w)
{
    __shared__ float ys[768];
    __shared__ float prt[8][33];
    int b = blockIdx.y, t = threadIdx.x;
    const float* xr = o0 + b * 768;
    for (int i = t; i < 768; i += 256) ys[i] = xr[i];
    __syncthreads();
    int c = blockIdx.x * 32 + (t & 31);
    int kg = t >> 5;
    float acc = 0.f;
    for (int k = kg; k < 768; k += 8) acc += ys[k] * Wo[(size_t)k * 768 + c];
    prt[kg][t & 31] = acc;
    __syncthreads();
    if (kg == 0) {
        float s = 0.f;
#pragma unroll
        for (int i = 0; i < 8; ++i) s += prt[i][t];
        x2w[b * 768 + c] = s + bo[c] + clsT[c];
    }
}

// grid (96, 8): f1 = relu(h @ W1 + b1)
__global__ __launch_bounds__(256) void t3_f1(
    const float* __restrict__ hw, const float* __restrict__ W1,
    const float* __restrict__ b1, float* __restrict__ f1w)
{
    __shared__ float ys[768];
    __shared__ float prt[8][33];
    int b = blockIdx.y, t = threadIdx.x;
    const float* xr = hw + b * 768;
    for (int i = t; i < 768; i += 256) ys[i] = xr[i];
    __syncthreads();
    int c = blockIdx.x * 32 + (t & 31);
    int kg = t >> 5;
    float acc = 0.f;
    for (int k = kg; k < 768; k += 8) acc += ys[k] * W1[(size_t)k * NFF + c];
    prt[kg][t & 31] = acc;
    __syncthreads();
    if (kg == 0) {
        float s = 0.f;
#pragma unroll
        for (int i = 0; i < 8; ++i) s += prt[i][t];
        f1w[b * NFF + c] = fmaxf(s + b1[c], 0.0f);
    }
}

// grid (24, 8): x3 = x2 + f1 @ W2 + b2
__global__ __launch_bounds__(256) void t4_x3(
    const float* __restrict__ f1w, const float* __restrict__ W2,
    const float* __restrict__ b2, const float* __restrict__ x2w,
    float* __restrict__ x3w)
{
    __shared__ float ys[3072];
    __shared__ float prt[8][33];
    int b = blockIdx.y, t = threadIdx.x;
    const float* xr = f1w + b * NFF;
    for (int i = t; i < NFF; i += 256) ys[i] = xr[i];
    __syncthreads();
    int c = blockIdx.x * 32 + (t & 31);
    int kg = t >> 5;
    float acc = 0.f;
    for (int k = kg; k < NFF; k += 8) acc += ys[k] * W2[(size_t)k * 768 + c];
    prt[kg][t & 31] = acc;
    __syncthreads();
    if (kg == 0) {
        float s = 0.f;
#pragma unroll
        for (int i = 0; i < 8; ++i) s += prt[i][t];
        x3w[b * 768 + c] = x2w[b * 768 + c] + s + b2[c];
    }
}

// grid 8: plain layer-norm of one 768 row (fp32, mirrors jnp op order)
__global__ __launch_bounds__(256) void ln_row(
    const float* __restrict__ in, const float* __restrict__ ga,
    const float* __restrict__ gb, float* __restrict__ outp)
{
    __shared__ float red[4];
    int b = blockIdx.x, t = threadIdx.x;
    const float* x = in + b * 768;
    float a0 = x[t], a1 = x[t + 256], a2 = x[t + 512];
    float mean = bsum256(a0 + a1 + a2, red) / 768.0f;
    float d0 = a0 - mean, d1 = a1 - mean, d2 = a2 - mean;
    float var = bsum256(d0 * d0 + d1 * d1 + d2 * d2, red) / 767.0f;
    float den = sqrtf(var) + 1e-6f;
    float* o = outp + b * 768;
    o[t] = (ga[t] * d0) / den + gb[t];
    o[t + 256] = (ga[t + 256] * d1) / den + gb[t + 256];
    o[t + 512] = (ga[t + 512] * d2) / den + gb[t + 512];
}

// ---------------------------------------------------------------------------
// Head: pool softmax, class logits, entropy -> adjusted_k, stable top-k rank,
// gather prompt_pool with keep mask. One block per batch.
__global__ __launch_bounds__(256) void head_kernel(
    const float* __restrict__ clsw, const float* __restrict__ Wpool,
    const float* __restrict__ bpool, const float* __restrict__ Wcls,
    const float* __restrict__ bcls, const float* __restrict__ pool,
    float* __restrict__ out)
{
    __shared__ float sC[768];
    __shared__ float sP[100];
    __shared__ float sC7[7];
    __shared__ int sTop[100];
    __shared__ int sKk;
    int b = blockIdx.x, t = threadIdx.x;
    for (int i = t; i < 768; i += 256) sC[i] = clsw[b * 768 + i];
    __syncthreads();
    if (t < 100) {
        float acc = bpool[t];
        for (int k = 0; k < 768; ++k) acc += sC[k] * Wpool[k * 100 + t];
        sP[t] = acc;
    } else if (t >= 128 && t < 135) {
        int c = t - 128;
        float acc = bcls[c];
        for (int k = 0; k < 768; ++k) acc += sC[k] * Wcls[k * 7 + c];
        sC7[c] = acc;
        out[OUT_CLS_OFF + b * 7 + c] = acc;
    }
    __syncthreads();
    float mx = sP[0];
    for (int j = 1; j < 100; ++j) mx = fmaxf(mx, sP[j]);
    float e = (t < 100) ? expf(sP[t] - mx) : 0.0f;
    __syncthreads();
    if (t < 100) sP[t] = e;
    __syncthreads();
    float zs = 0.f;
    for (int j = 0; j < 100; ++j) zs += sP[j];
    __syncthreads();
    if (t < 100) sP[t] = e / zs;
    __syncthreads();
    if (t == 0) {
        float m7 = sC7[0];
        for (int j = 1; j < 7; ++j) m7 = fmaxf(m7, sC7[j]);
        float es[7]; float z = 0.f;
        for (int j = 0; j < 7; ++j) { es[j] = expf(sC7[j] - m7); z += es[j]; }
        float ent = 0.f;
        for (int j = 0; j < 7; ++j) { float pr = es[j] / z; ent -= pr * logf(pr + 1e-9f); }
        float ne = ent / logf(7.0f);
        int kk = (int)floorf(1.0f + ne * 99.0f);
        sKk = kk < 1 ? 1 : (kk > 100 ? 100 : kk);
    }
    if (t < 100) {
        float pi = sP[t];
        int r = 0;
        for (int j = 0; j < 100; ++j) {
            float pj = sP[j];
            r += (pj > pi) || (pj == pi && j < t);
        }
        sTop[r] = t;   // descending, stable (lower index first on ties)
    }
    __syncthreads();
    int kk = sKk;
    float* ob = out + (size_t)b * 76800;
    for (int r = 0; r < 100; ++r) {
        const float* src = pool + (size_t)sTop[r] * 768;
        bool keep = r < kk;
        for (int d = t; d < 768; d += 256) ob[r * 768 + d] = keep ? src[d] : 0.0f;
    }
}

// ---------------------------------------------------------------------------
extern "C" void kernel_launch(void* const* d_in, const int* in_sizes, int n_in,
                              void* d_out, int out_size, void* d_ws, size_t ws_size,
                              hipStream_t stream) {
    (void)in_sizes; (void)n_in; (void)out_size; (void)ws_size;
    const float* tf    = (const float*)d_in[0];
    const float* pool  = (const float*)d_in[1];
    const float* clsT  = (const float*)d_in[2];
    const float* Wq    = (const float*)d_in[3];
    const float* bq    = (const float*)d_in[4];
    const float* Wk    = (const float*)d_in[5];
    const float* bk    = (const float*)d_in[6];
    const float* Wv    = (const float*)d_in[7];
    const float* bv    = (const float*)d_in[8];
    const float* Wo    = (const float*)d_in[9];
    const float* bo    = (const float*)d_in[10];
    const float* ln1a  = (const float*)d_in[11];
    const float* ln1b  = (const float*)d_in[12];
    const float* ln2a  = (const float*)d_in[13];
    const float* ln2b  = (const float*)d_in[14];
    const float* W1    = (const float*)d_in[15];
    const float* b1    = (const float*)d_in[16];
    const float* W2    = (const float*)d_in[17];
    const float* b2    = (const float*)d_in[18];
    const float* lnfa  = (const float*)d_in[19];
    const float* lnfb  = (const float*)d_in[20];
    const float* Wpool = (const float*)d_in[21];
    const float* bpool = (const float*)d_in[22];
    const float* Wcls  = (const float*)d_in[23];
    const float* bcls  = (const float*)d_in[24];
    float* out = (float*)d_out;
    char* ws = (char*)d_ws;

    u16*   Bth  = (u16*)(ws + 0);           //  2,359,296 B
    u16*   Btl  = (u16*)(ws + 2359296);     //  2,359,296
    u16*   Ahi  = (u16*)(ws + 4718592);     // 12,582,912
    u16*   Alo  = (u16*)(ws + 17301504);    // 12,582,912
    float* kv   = (float*)(ws + 29884416);  // 50,331,648
    float* y0   = (float*)(ws + 80216064);  //      3,072
    float* q0   = (float*)(ws + 80219136);  //      3,072
    float* o0   = (float*)(ws + 80222208);  //     24,576
    float* x2w  = (float*)(ws + 80246784);  //     24,576
    float* hw   = (float*)(ws + 80271360);  //     24,576
    float* f1w  = (float*)(ws + 80295936);  //     98,304
    float* x3w  = (float*)(ws + 80394240);  //     24,576
    float* clsw = (float*)(ws + 80418816);  //     24,576  (total ~80.4 MB)

    prep_weights<<<dim3(24, 12), 256, 0, stream>>>(Wk, Wv, Bth, Btl);
    ln1_split<<<8192, 256, 0, stream>>>(tf, clsT, ln1a, ln1b, Ahi, Alo, y0);
    kv_gemm<<<dim3(64, 12), 256, 0, stream>>>(Ahi, Alo, Bth, Btl, bk, bv, kv);
    q0_kernel<<<24, 256, 0, stream>>>(y0, Wq, bq, q0);
    attn0_kernel<<<128, 1024, 0, stream>>>(kv, q0, o0);
    t1_x2<<<dim3(24, 8), 256, 0, stream>>>(o0, Wo, bo, clsT, x2w);
    ln_row<<<8, 256, 0, stream>>>(x2w, ln2a, ln2b, hw);
    t3_f1<<<dim3(96, 8), 256, 0, stream>>>(hw, W1, b1, f1w);
    t4_x3<<<dim3(24, 8), 256, 0, stream>>>(f1w, W2, b2, x2w, x3w);
    ln_row<<<8, 256, 0, stream>>>(x3w, lnfa, lnfb, clsw);
    head_kernel<<<8, 256, 0, stream>>>(clsw, Wpool, bpool, Wcls, bcls, pool, out);
}

// Round 3
// 223.190 us; speedup vs baseline: 1.9292x; 1.9292x over previous
//
#include <hip/hip_runtime.h>

// ---------------------------------------------------------------------------
// PromptSelector — collapsed-algebra version.
// Outputs depend only on the CLS row. K/V GEMMs are algebraically folded:
//   scores[b,h,j] = Xln[b,j,:] . wkq[:,h] + c[h]     (wkq = Wk_h @ q0_h /√48)
//   o[b,h,:]      = (Σ_j p_j Xln[b,j,:]) @ Wv_h + bv_h
// Two streaming passes over X (25 MB each) + small fp32 GEMVs. No MFMA.
// Head (discrete decisions) accumulates in double.
// ---------------------------------------------------------------------------

#define OUT_CLS_OFF 614400   // 8*100*768

// block-wide (256 thr) sum reduce; red must hold >=4 floats
__device__ __forceinline__ float bsum256(float v, float* red) {
    int lane = threadIdx.x & 63, w = threadIdx.x >> 6;
#pragma unroll
    for (int off = 1; off < 64; off <<= 1) v += __shfl_xor(v, off);
    __syncthreads();
    if (lane == 0) red[w] = v;
    __syncthreads();
    return red[0] + red[1] + red[2] + red[3];
}
__device__ __forceinline__ float bmax256(float v, float* red) {
    int lane = threadIdx.x & 63, w = threadIdx.x >> 6;
#pragma unroll
    for (int off = 1; off < 64; off <<= 1) v = fmaxf(v, __shfl_xor(v, off));
    __syncthreads();
    if (lane == 0) red[w] = v;
    __syncthreads();
    return fmaxf(fmaxf(red[0], red[1]), fmaxf(red[2], red[3]));
}

// ---------------------------------------------------------------------------
// plain fp32 layer-norm of one 768-row per block (mirrors jnp op order)
__global__ __launch_bounds__(256) void ln_row(
    const float* __restrict__ in, const float* __restrict__ ga,
    const float* __restrict__ gb, float* __restrict__ outp)
{
    __shared__ float red[4];
    int b = blockIdx.x, t = threadIdx.x;
    const float* x = in + (size_t)b * 768;
    float a0 = x[t], a1 = x[t + 256], a2 = x[t + 512];
    float mean = bsum256(a0 + a1 + a2, red) * (1.0f / 768.0f);
    float d0 = a0 - mean, d1 = a1 - mean, d2 = a2 - mean;
    float var = bsum256(d0 * d0 + d1 * d1 + d2 * d2, red) * (1.0f / 767.0f);
    float den = sqrtf(var) + 1e-6f;
    float* o = outp + (size_t)b * 768;
    o[t]       = (ga[t] * d0) / den + gb[t];
    o[t + 256] = (ga[t + 256] * d1) / den + gb[t + 256];
    o[t + 512] = (ga[t + 512] * d2) / den + gb[t + 512];
}

// ---------------------------------------------------------------------------
// generic 768->768 GEMV pattern: q0 = y0 @ Wq + bq.  grid 12, block 256.
// 64 cols/block (16 thr x float4), 16 k-groups x 48.
__global__ __launch_bounds__(256) void q0_gemv(
    const float* __restrict__ y0, const float* __restrict__ Wq,
    const float* __restrict__ bq, float* __restrict__ q0)
{
    __shared__ float ys[768];
    __shared__ float4 part[16][17];
    int t = threadIdx.x;
    ys[t] = y0[t]; ys[t + 256] = y0[t + 256]; ys[t + 512] = y0[t + 512];
    __syncthreads();
    int c = blockIdx.x * 64 + (t & 15) * 4;
    int kq = t >> 4;
    float4 acc = {0.f, 0.f, 0.f, 0.f};
#pragma unroll 8
    for (int i = 0; i < 48; ++i) {
        int k = kq * 48 + i;
        float4 w = *(const float4*)&Wq[(size_t)k * 768 + c];
        float y = ys[k];
        acc.x = fmaf(y, w.x, acc.x); acc.y = fmaf(y, w.y, acc.y);
        acc.z = fmaf(y, w.z, acc.z); acc.w = fmaf(y, w.w, acc.w);
    }
    part[kq][t & 15] = acc;
    __syncthreads();
    if (t < 16) {
        float4 s = {0.f, 0.f, 0.f, 0.f};
#pragma unroll
        for (int i = 0; i < 16; ++i) {
            float4 v = part[i][t];
            s.x += v.x; s.y += v.y; s.z += v.z; s.w += v.w;
        }
        int cc = blockIdx.x * 64 + t * 4;
        float4 b4 = *(const float4*)&bq[cc];
        q0[cc] = s.x + b4.x; q0[cc + 1] = s.y + b4.y;
        q0[cc + 2] = s.z + b4.z; q0[cc + 3] = s.w + b4.w;
    }
}

// ---------------------------------------------------------------------------
// wkq[k][h] = (Wk[k, h*48..+48] . q0[h*48..+48]) / sqrt(48); +16 bias terms.
// grid 48 x 256: thread = (kl = t>>4, h = t&15).
__global__ __launch_bounds__(256) void wkq_prep(
    const float* __restrict__ Wk, const float* __restrict__ bk,
    const float* __restrict__ q0, float* __restrict__ wkqc)
{
    __shared__ float qs[768];
    int t = threadIdx.x;
    qs[t] = q0[t]; qs[t + 256] = q0[t + 256]; qs[t + 512] = q0[t + 512];
    __syncthreads();
    const float invs = 0.14433756729740643f;  // 1/sqrt(48)
    int kl = t >> 4, h = t & 15;
    int k = blockIdx.x * 16 + kl;
    const float* wr = Wk + (size_t)k * 768 + h * 48;
    const float* qh = qs + h * 48;
    float a = 0.f;
#pragma unroll
    for (int d = 0; d < 48; d += 4) {
        float4 w = *(const float4*)&wr[d];
        a += w.x * qh[d] + w.y * qh[d + 1] + w.z * qh[d + 2] + w.w * qh[d + 3];
    }
    wkqc[k * 16 + h] = a * invs;
    if (blockIdx.x == 0 && t < 16) {
        float c = 0.f;
        for (int d = 0; d < 48; ++d) c += bk[t * 48 + d] * qs[t * 48 + d];
        wkqc[12288 + t] = c * invs;
    }
}

// ---------------------------------------------------------------------------
// Pass 1: fused LN1 + 16-head score GEMV for all 8192 rows.
// grid 512 (16 rows/block). Saves (mean, rden) per row for pass 2.
__global__ __launch_bounds__(256) void ln_scores(
    const float* __restrict__ tf, const float* __restrict__ clsT,
    const float* __restrict__ ga, const float* __restrict__ gb,
    const float* __restrict__ wkqc, float* __restrict__ sc,
    float2* __restrict__ stats)
{
    __shared__ float wk[768 * 17];   // [d][17], cols 0..15 used (52.2 KB)
    __shared__ float xs[768];
    __shared__ float part[4][16];
    __shared__ float red[4];
    __shared__ float c16[16];
    int t = threadIdx.x;
    for (int i = t; i < 12288; i += 256) wk[(i >> 4) * 17 + (i & 15)] = wkqc[i];
    if (t < 16) c16[t] = wkqc[12288 + t];
    __syncthreads();

    int r0 = blockIdx.x * 16;
    int lane = t & 63, w = t >> 6;
    int hh = t & 15, dg = t >> 4;     // dot-phase role
    float ga0 = ga[t], ga1 = ga[t + 256], ga2 = ga[t + 512];
    float gb0 = gb[t], gb1 = gb[t + 256], gb2 = gb[t + 512];

    for (int r = 0; r < 16; ++r) {
        int row = r0 + r;
        int b = row >> 10, j = row & 1023;
        const float* src = j ? (tf + ((size_t)b * 1023 + (j - 1)) * 768) : clsT;
        float x0 = src[t], x1 = src[t + 256], x2 = src[t + 512];
        float mean = bsum256(x0 + x1 + x2, red) * (1.0f / 768.0f);
        float d0 = x0 - mean, d1 = x1 - mean, d2 = x2 - mean;
        float var = bsum256(d0 * d0 + d1 * d1 + d2 * d2, red) * (1.0f / 767.0f);
        float rden = 1.0f / (sqrtf(var) + 1e-6f);
        xs[t]       = (ga0 * d0) * rden + gb0;
        xs[t + 256] = (ga1 * d1) * rden + gb1;
        xs[t + 512] = (ga2 * d2) * rden + gb2;
        if (t == 0) stats[row] = make_float2(mean, rden);
        __syncthreads();
        // dot: thread (hh, dg) covers d = dg*48 .. +48 for head hh
        float a = 0.f;
        int dbase = dg * 48;
#pragma unroll
        for (int i = 0; i < 48; ++i) a = fmaf(xs[dbase + i], wk[(dbase + i) * 17 + hh], a);
        a += __shfl_xor(a, 16);
        a += __shfl_xor(a, 32);
        if ((lane >> 4) == 0) part[w][hh] = a;
        __syncthreads();
        if (t < 16) {
            float sv = part[0][t] + part[1][t] + part[2][t] + part[3][t] + c16[t];
            sc[(((size_t)b * 16 + t) << 10) + j] = sv;
        }
        // next row's first bsum barrier protects xs/part reuse
    }
}

// ---------------------------------------------------------------------------
// softmax over j (1024) per (b,h). grid 128.
__global__ __launch_bounds__(256) void softmax_k(
    const float* __restrict__ sc, float* __restrict__ p)
{
    __shared__ float red[4];
    int bh = blockIdx.x, t = threadIdx.x;
    const float4* s4 = (const float4*)(sc + ((size_t)bh << 10));
    float4 v = s4[t];
    float m = fmaxf(fmaxf(v.x, v.y), fmaxf(v.z, v.w));
    float M = bmax256(m, red);
    float e0 = expf(v.x - M), e1 = expf(v.y - M), e2 = expf(v.z - M), e3 = expf(v.w - M);
    float Z = bsum256(e0 + e1 + e2 + e3, red);
    float4 o; o.x = e0 / Z; o.y = e1 / Z; o.z = e2 / Z; o.w = e3 / Z;
    ((float4*)(p + ((size_t)bh << 10)))[t] = o;
}

// ---------------------------------------------------------------------------
// Pass 2: partial u[b,h,:] = Σ_j p[b,h,j]*Xln[b,j,:] over a 64-row j-chunk.
// grid 128 = (b 8) x (jc 16). LN recomputed from saved stats.
__global__ __launch_bounds__(256) void upart_k(
    const float* __restrict__ tf, const float* __restrict__ clsT,
    const float2* __restrict__ stats, const float* __restrict__ ga,
    const float* __restrict__ gb, const float* __restrict__ p,
    float* __restrict__ up)
{
    __shared__ float ps[16][64];
    int b = blockIdx.x & 7, jc = blockIdx.x >> 3;
    int t = threadIdx.x;
    {   // stage p[16][64] slice
        int h = t >> 4, j4 = (t & 15) * 4;
        const float* prow = p + (((size_t)b * 16 + h) << 10) + jc * 64 + j4;
        float4 pv = *(const float4*)prow;
        ps[h][j4] = pv.x; ps[h][j4 + 1] = pv.y; ps[h][j4 + 2] = pv.z; ps[h][j4 + 3] = pv.w;
    }
    __syncthreads();
    float ga0 = ga[t], ga1 = ga[t + 256], ga2 = ga[t + 512];
    float gb0 = gb[t], gb1 = gb[t + 256], gb2 = gb[t + 512];
    float acc[16][3];
#pragma unroll
    for (int h = 0; h < 16; ++h) { acc[h][0] = 0.f; acc[h][1] = 0.f; acc[h][2] = 0.f; }

    for (int jj = 0; jj < 64; ++jj) {
        int j = jc * 64 + jj;
        const float* src = j ? (tf + ((size_t)b * 1023 + (j - 1)) * 768) : clsT;
        float2 st = stats[(b << 10) + j];
        float x0 = src[t], x1 = src[t + 256], x2 = src[t + 512];
        float xl0 = (ga0 * (x0 - st.x)) * st.y + gb0;
        float xl1 = (ga1 * (x1 - st.x)) * st.y + gb1;
        float xl2 = (ga2 * (x2 - st.x)) * st.y + gb2;
#pragma unroll
        for (int h = 0; h < 16; ++h) {
            float ph = ps[h][jj];
            acc[h][0] = fmaf(ph, xl0, acc[h][0]);
            acc[h][1] = fmaf(ph, xl1, acc[h][1]);
            acc[h][2] = fmaf(ph, xl2, acc[h][2]);
        }
    }
    float* o = up + (((size_t)b * 16 + jc) * 16) * 768;
#pragma unroll
    for (int h = 0; h < 16; ++h) {
        o[h * 768 + t] = acc[h][0];
        o[h * 768 + t + 256] = acc[h][1];
        o[h * 768 + t + 512] = acc[h][2];
    }
}

// ---------------------------------------------------------------------------
// reduce 16 u-partials, then o0 head-slice = u @ Wv[:,h*48..+48] + bv.
// grid (16 h, 8 b).
__global__ __launch_bounds__(256) void o0_k(
    const float* __restrict__ up, const float* __restrict__ Wv,
    const float* __restrict__ bv, float* __restrict__ o0)
{
    __shared__ float us[768];
    __shared__ float part[4][64];
    int h = blockIdx.x, b = blockIdx.y, t = threadIdx.x;
    float s0 = 0.f, s1 = 0.f, s2 = 0.f;
#pragma unroll
    for (int jc = 0; jc < 16; ++jc) {
        const float* q = up + (((size_t)b * 16 + jc) * 16 + h) * 768;
        s0 += q[t]; s1 += q[t + 256]; s2 += q[t + 512];
    }
    us[t] = s0; us[t + 256] = s1; us[t + 512] = s2;
    __syncthreads();
    int dd = t & 63, kg = t >> 6;    // 4 groups x 192 k
    float a = 0.f;
    if (dd < 48) {
#pragma unroll 8
        for (int i = 0; i < 192; ++i) {
            int k = kg * 192 + i;
            a = fmaf(us[k], Wv[(size_t)k * 768 + h * 48 + dd], a);
        }
    }
    part[kg][dd] = a;
    __syncthreads();
    if (t < 48)
        o0[(size_t)b * 768 + h * 48 + t] =
            part[0][t] + part[1][t] + part[2][t] + part[3][t] + bv[h * 48 + t];
}

// ---------------------------------------------------------------------------
// x2 = clsT + o0 @ Wo + bo. grid (12, 8).
__global__ __launch_bounds__(256) void x2_k(
    const float* __restrict__ o0, const float* __restrict__ Wo,
    const float* __restrict__ bo, const float* __restrict__ clsT,
    float* __restrict__ x2w)
{
    __shared__ float ys[768];
    __shared__ float4 part[16][17];
    int b = blockIdx.y, t = threadIdx.x;
    const float* xr = o0 + (size_t)b * 768;
    ys[t] = xr[t]; ys[t + 256] = xr[t + 256]; ys[t + 512] = xr[t + 512];
    __syncthreads();
    int c = blockIdx.x * 64 + (t & 15) * 4;
    int kq = t >> 4;
    float4 acc = {0.f, 0.f, 0.f, 0.f};
#pragma unroll 8
    for (int i = 0; i < 48; ++i) {
        int k = kq * 48 + i;
        float4 w = *(const float4*)&Wo[(size_t)k * 768 + c];
        float y = ys[k];
        acc.x = fmaf(y, w.x, acc.x); acc.y = fmaf(y, w.y, acc.y);
        acc.z = fmaf(y, w.z, acc.z); acc.w = fmaf(y, w.w, acc.w);
    }
    part[kq][t & 15] = acc;
    __syncthreads();
    if (t < 16) {
        float4 s = {0.f, 0.f, 0.f, 0.f};
#pragma unroll
        for (int i = 0; i < 16; ++i) {
            float4 v = part[i][t];
            s.x += v.x; s.y += v.y; s.z += v.z; s.w += v.w;
        }
        int cc = blockIdx.x * 64 + t * 4;
        float4 b4 = *(const float4*)&bo[cc];
        float4 r4 = *(const float4*)&clsT[cc];
        float* o = x2w + (size_t)b * 768 + cc;
        o[0] = s.x + b4.x + r4.x; o[1] = s.y + b4.y + r4.y;
        o[2] = s.z + b4.z + r4.z; o[3] = s.w + b4.w + r4.w;
    }
}

// ---------------------------------------------------------------------------
// f1 = relu(h @ W1 + b1). grid (24, 8): 128 cols/block, 8 k-groups x 96.
__global__ __launch_bounds__(256) void f1_k(
    const float* __restrict__ hw, const float* __restrict__ W1,
    const float* __restrict__ b1, float* __restrict__ f1w)
{
    __shared__ float ys[768];
    __shared__ float4 part[8][33];
    int b = blockIdx.y, t = threadIdx.x;
    const float* xr = hw + (size_t)b * 768;
    ys[t] = xr[t]; ys[t + 256] = xr[t + 256]; ys[t + 512] = xr[t + 512];
    __syncthreads();
    int c = blockIdx.x * 128 + (t & 31) * 4;
    int kq = t >> 5;
    float4 acc = {0.f, 0.f, 0.f, 0.f};
#pragma unroll 8
    for (int i = 0; i < 96; ++i) {
        int k = kq * 96 + i;
        float4 w = *(const float4*)&W1[(size_t)k * 3072 + c];
        float y = ys[k];
        acc.x = fmaf(y, w.x, acc.x); acc.y = fmaf(y, w.y, acc.y);
        acc.z = fmaf(y, w.z, acc.z); acc.w = fmaf(y, w.w, acc.w);
    }
    part[kq][t & 31] = acc;
    __syncthreads();
    if (t < 32) {
        float4 s = {0.f, 0.f, 0.f, 0.f};
#pragma unroll
        for (int i = 0; i < 8; ++i) {
            float4 v = part[i][t];
            s.x += v.x; s.y += v.y; s.z += v.z; s.w += v.w;
        }
        int cc = blockIdx.x * 128 + t * 4;
        float4 b4 = *(const float4*)&b1[cc];
        float* o = f1w + (size_t)b * 3072 + cc;
        o[0] = fmaxf(s.x + b4.x, 0.f); o[1] = fmaxf(s.y + b4.y, 0.f);
        o[2] = fmaxf(s.z + b4.z, 0.f); o[3] = fmaxf(s.w + b4.w, 0.f);
    }
}

// ---------------------------------------------------------------------------
// x3 = x2 + f1 @ W2 + b2. grid (12, 8): 64 cols/block, 16 k-groups x 192.
__global__ __launch_bounds__(256) void x3_k(
    const float* __restrict__ f1w, const float* __restrict__ W2,
    const float* __restrict__ b2, const float* __restrict__ x2w,
    float* __restrict__ x3w)
{
    __shared__ float ys[3072];
    __shared__ float4 part[16][17];
    int b = blockIdx.y, t = threadIdx.x;
    const float* xr = f1w + (size_t)b * 3072;
    for (int i = t; i < 3072; i += 256) ys[i] = xr[i];
    __syncthreads();
    int c = blockIdx.x * 64 + (t & 15) * 4;
    int kq = t >> 4;
    float4 acc = {0.f, 0.f, 0.f, 0.f};
#pragma unroll 8
    for (int i = 0; i < 192; ++i) {
        int k = kq * 192 + i;
        float4 w = *(const float4*)&W2[(size_t)k * 768 + c];
        float y = ys[k];
        acc.x = fmaf(y, w.x, acc.x); acc.y = fmaf(y, w.y, acc.y);
        acc.z = fmaf(y, w.z, acc.z); acc.w = fmaf(y, w.w, acc.w);
    }
    part[kq][t & 15] = acc;
    __syncthreads();
    if (t < 16) {
        float4 s = {0.f, 0.f, 0.f, 0.f};
#pragma unroll
        for (int i = 0; i < 16; ++i) {
            float4 v = part[i][t];
            s.x += v.x; s.y += v.y; s.z += v.z; s.w += v.w;
        }
        int cc = blockIdx.x * 64 + t * 4;
        float4 b4 = *(const float4*)&b2[cc];
        const float* x2r = x2w + (size_t)b * 768 + cc;
        float* o = x3w + (size_t)b * 768 + cc;
        o[0] = x2r[0] + s.x + b4.x; o[1] = x2r[1] + s.y + b4.y;
        o[2] = x2r[2] + s.z + b4.z; o[3] = x2r[3] + s.w + b4.w;
    }
}

// ---------------------------------------------------------------------------
// Head: pool softmax, class logits, entropy -> adjusted_k, stable top-k rank,
// gather prompt_pool with keep mask. One block per batch.
// FIXED vs round 2: class-GEMV threads are t in [200,256) (56 threads for
// partC[8][7]); previously [208,264) left 8 partials as garbage LDS.
// Logits / softmax / entropy accumulate in double (discrete decisions).
__global__ __launch_bounds__(256) void head_kernel(
    const float* __restrict__ clsw, const float* __restrict__ Wpool,
    const float* __restrict__ bpool, const float* __restrict__ Wcls,
    const float* __restrict__ bcls, const float* __restrict__ pool,
    float* __restrict__ out)
{
    __shared__ float sC[768];
    __shared__ double sP[100];
    __shared__ double sC7[7];
    __shared__ int sTop[100];
    __shared__ int sKk;
    __shared__ double partP[2][100];
    __shared__ double partC[8][7];
    int b = blockIdx.x, t = threadIdx.x;
    for (int i = t; i < 768; i += 256) sC[i] = clsw[(size_t)b * 768 + i];
    __syncthreads();
    if (t < 200) {
        int kg = (t >= 100) ? 1 : 0;
        int c = t - kg * 100;
        double a = 0.0;
#pragma unroll 8
        for (int i = 0; i < 384; ++i) {
            int k = kg * 384 + i;
            a = fma((double)sC[k], (double)Wpool[k * 100 + c], a);
        }
        partP[kg][c] = a;
    } else {                       // t in [200, 256): exactly 56 threads
        int idx = t - 200;         // 0..55
        int kg = idx / 7, c = idx - kg * 7;   // kg 0..7, c 0..6
        double a = 0.0;
#pragma unroll 8
        for (int i = 0; i < 96; ++i) {
            int k = kg * 96 + i;
            a = fma((double)sC[k], (double)Wcls[k * 7 + c], a);
        }
        partC[kg][c] = a;
    }
    __syncthreads();
    if (t < 100) sP[t] = partP[0][t] + partP[1][t] + (double)bpool[t];
    if (t >= 128 && t < 135) {
        int c = t - 128;
        double a = (double)bcls[c];
#pragma unroll
        for (int kg = 0; kg < 8; ++kg) a += partC[kg][c];
        sC7[c] = a;
        out[OUT_CLS_OFF + b * 7 + c] = (float)a;
    }
    __syncthreads();
    double mx = sP[0];
    for (int j = 1; j < 100; ++j) mx = fmax(mx, sP[j]);
    double e = (t < 100) ? exp(sP[t] - mx) : 0.0;
    __syncthreads();
    if (t < 100) sP[t] = e;
    __syncthreads();
    double zs = 0.0;
    for (int j = 0; j < 100; ++j) zs += sP[j];
    __syncthreads();
    if (t < 100) sP[t] = e / zs;
    __syncthreads();
    if (t == 0) {
        double m7 = sC7[0];
        for (int j = 1; j < 7; ++j) m7 = fmax(m7, sC7[j]);
        double es[7]; double z = 0.0;
        for (int j = 0; j < 7; ++j) { es[j] = exp(sC7[j] - m7); z += es[j]; }
        double ent = 0.0;
        for (int j = 0; j < 7; ++j) { double pr = es[j] / z; ent -= pr * log(pr + 1e-9); }
        double ne = ent / log(7.0);
        int kk = (int)floor(1.0 + ne * 99.0);
        sKk = kk < 1 ? 1 : (kk > 100 ? 100 : kk);
    }
    if (t < 100) {
        double pi = sP[t];
        int r = 0;
        for (int j = 0; j < 100; ++j) {
            double pj = sP[j];
            r += (pj > pi) || (pj == pi && j < t);
        }
        sTop[r] = t;   // descending, stable (lower index first on ties)
    }
    __syncthreads();
    int kk = sKk;
    float* ob = out + (size_t)b * 76800;
    for (int r = 0; r < 100; ++r) {
        const float* src = pool + (size_t)sTop[r] * 768;
        bool keep = r < kk;
        for (int d = t; d < 768; d += 256) ob[r * 768 + d] = keep ? src[d] : 0.0f;
    }
}

// ---------------------------------------------------------------------------
extern "C" void kernel_launch(void* const* d_in, const int* in_sizes, int n_in,
                              void* d_out, int out_size, void* d_ws, size_t ws_size,
                              hipStream_t stream) {
    (void)in_sizes; (void)n_in; (void)out_size; (void)ws_size;
    const float* tf    = (const float*)d_in[0];
    const float* pool  = (const float*)d_in[1];
    const float* clsT  = (const float*)d_in[2];
    const float* Wq    = (const float*)d_in[3];
    const float* bq    = (const float*)d_in[4];
    const float* Wk    = (const float*)d_in[5];
    const float* bk    = (const float*)d_in[6];
    const float* Wv    = (const float*)d_in[7];
    const float* bv    = (const float*)d_in[8];
    const float* Wo    = (const float*)d_in[9];
    const float* bo    = (const float*)d_in[10];
    const float* ln1a  = (const float*)d_in[11];
    const float* ln1b  = (const float*)d_in[12];
    const float* ln2a  = (const float*)d_in[13];
    const float* ln2b  = (const float*)d_in[14];
    const float* W1    = (const float*)d_in[15];
    const float* b1    = (const float*)d_in[16];
    const float* W2    = (const float*)d_in[17];
    const float* b2    = (const float*)d_in[18];
    const float* lnfa  = (const float*)d_in[19];
    const float* lnfb  = (const float*)d_in[20];
    const float* Wpool = (const float*)d_in[21];
    const float* bpool = (const float*)d_in[22];
    const float* Wcls  = (const float*)d_in[23];
    const float* bcls  = (const float*)d_in[24];
    float* out = (float*)d_out;
    char* ws = (char*)d_ws;

    float*  sc    = (float*)(ws + 0);          // 524,288 B (128 x 1024)
    float*  p     = (float*)(ws + 524288);     // 524,288
    float2* stats = (float2*)(ws + 1048576);   // 65,536
    float*  wkqc  = (float*)(ws + 1114112);    // 49,408 (12288 + 16, padded)
    float*  y0    = (float*)(ws + 1163520);    // 3,072
    float*  q0    = (float*)(ws + 1166592);    // 3,072
    float*  upart = (float*)(ws + 1169664);    // 6,291,456 (8 x 16 x 16 x 768)
    float*  o0    = (float*)(ws + 7461120);    // 24,576
    float*  x2w   = (float*)(ws + 7485696);    // 24,576
    float*  hw    = (float*)(ws + 7510272);    // 24,576
    float*  f1w   = (float*)(ws + 7534848);    // 98,304
    float*  x3w   = (float*)(ws + 7633152);    // 24,576
    float*  clsw  = (float*)(ws + 7657728);    // 24,576  (total ~7.7 MB)

    ln_row<<<1, 256, 0, stream>>>(clsT, ln1a, ln1b, y0);
    q0_gemv<<<12, 256, 0, stream>>>(y0, Wq, bq, q0);
    wkq_prep<<<48, 256, 0, stream>>>(Wk, bk, q0, wkqc);
    ln_scores<<<512, 256, 0, stream>>>(tf, clsT, ln1a, ln1b, wkqc, sc, stats);
    softmax_k<<<128, 256, 0, stream>>>(sc, p);
    upart_k<<<128, 256, 0, stream>>>(tf, clsT, stats, ln1a, ln1b, p, upart);
    o0_k<<<dim3(16, 8), 256, 0, stream>>>(upart, Wv, bv, o0);
    x2_k<<<dim3(12, 8), 256, 0, stream>>>(o0, Wo, bo, clsT, x2w);
    ln_row<<<8, 256, 0, stream>>>(x2w, ln2a, ln2b, hw);
    f1_k<<<dim3(24, 8), 256, 0, stream>>>(hw, W1, b1, f1w);
    x3_k<<<dim3(12, 8), 256, 0, stream>>>(f1w, W2, b2, x2w, x3w);
    ln_row<<<8, 256, 0, stream>>>(x3w, lnfa, lnfb, clsw);
    head_kernel<<<8, 256, 0, stream>>>(clsw, Wpool, bpool, Wcls, bcls, pool, out);
}

// Round 4
// 154.674 us; speedup vs baseline: 2.7838x; 1.4430x over previous
//
#include <hip/hip_runtime.h>

// ---------------------------------------------------------------------------
// PromptSelector — collapsed-algebra version.
// Outputs depend only on the CLS row. K/V GEMMs are algebraically folded:
//   scores[b,h,j] = Xln[b,j,:] . wkq[:,h] + c[h]     (wkq = Wk_h @ q0_h /√48)
//   o[b,h,:]      = (Σ_j p_j Xln[b,j,:]) @ Wv_h + bv_h
// Two streaming passes over X (25 MB each) + small fp32 GEMVs. No MFMA.
// Head (discrete decisions) accumulates in double; the 2.5 MB prompt gather
// is a separate 800-block kernel (round-3's 128 µs was 8 blocks serially
// chasing load->store latency).
// ---------------------------------------------------------------------------

#define OUT_CLS_OFF 614400   // 8*100*768

// block-wide (256 thr) sum reduce; red must hold >=4 floats
__device__ __forceinline__ float bsum256(float v, float* red) {
    int lane = threadIdx.x & 63, w = threadIdx.x >> 6;
#pragma unroll
    for (int off = 1; off < 64; off <<= 1) v += __shfl_xor(v, off);
    __syncthreads();
    if (lane == 0) red[w] = v;
    __syncthreads();
    return red[0] + red[1] + red[2] + red[3];
}
__device__ __forceinline__ float bmax256(float v, float* red) {
    int lane = threadIdx.x & 63, w = threadIdx.x >> 6;
#pragma unroll
    for (int off = 1; off < 64; off <<= 1) v = fmaxf(v, __shfl_xor(v, off));
    __syncthreads();
    if (lane == 0) red[w] = v;
    __syncthreads();
    return fmaxf(fmaxf(red[0], red[1]), fmaxf(red[2], red[3]));
}

// ---------------------------------------------------------------------------
// plain fp32 layer-norm of one 768-row per block (mirrors jnp op order)
__global__ __launch_bounds__(256) void ln_row(
    const float* __restrict__ in, const float* __restrict__ ga,
    const float* __restrict__ gb, float* __restrict__ outp)
{
    __shared__ float red[4];
    int b = blockIdx.x, t = threadIdx.x;
    const float* x = in + (size_t)b * 768;
    float a0 = x[t], a1 = x[t + 256], a2 = x[t + 512];
    float mean = bsum256(a0 + a1 + a2, red) * (1.0f / 768.0f);
    float d0 = a0 - mean, d1 = a1 - mean, d2 = a2 - mean;
    float var = bsum256(d0 * d0 + d1 * d1 + d2 * d2, red) * (1.0f / 767.0f);
    float den = sqrtf(var) + 1e-6f;
    float* o = outp + (size_t)b * 768;
    o[t]       = (ga[t] * d0) / den + gb[t];
    o[t + 256] = (ga[t + 256] * d1) / den + gb[t + 256];
    o[t + 512] = (ga[t + 512] * d2) / den + gb[t + 512];
}

// ---------------------------------------------------------------------------
// generic 768->768 GEMV pattern: q0 = y0 @ Wq + bq.  grid 12, block 256.
// 64 cols/block (16 thr x float4), 16 k-groups x 48.
__global__ __launch_bounds__(256) void q0_gemv(
    const float* __restrict__ y0, const float* __restrict__ Wq,
    const float* __restrict__ bq, float* __restrict__ q0)
{
    __shared__ float ys[768];
    __shared__ float4 part[16][17];
    int t = threadIdx.x;
    ys[t] = y0[t]; ys[t + 256] = y0[t + 256]; ys[t + 512] = y0[t + 512];
    __syncthreads();
    int c = blockIdx.x * 64 + (t & 15) * 4;
    int kq = t >> 4;
    float4 acc = {0.f, 0.f, 0.f, 0.f};
#pragma unroll 8
    for (int i = 0; i < 48; ++i) {
        int k = kq * 48 + i;
        float4 w = *(const float4*)&Wq[(size_t)k * 768 + c];
        float y = ys[k];
        acc.x = fmaf(y, w.x, acc.x); acc.y = fmaf(y, w.y, acc.y);
        acc.z = fmaf(y, w.z, acc.z); acc.w = fmaf(y, w.w, acc.w);
    }
    part[kq][t & 15] = acc;
    __syncthreads();
    if (t < 16) {
        float4 s = {0.f, 0.f, 0.f, 0.f};
#pragma unroll
        for (int i = 0; i < 16; ++i) {
            float4 v = part[i][t];
            s.x += v.x; s.y += v.y; s.z += v.z; s.w += v.w;
        }
        int cc = blockIdx.x * 64 + t * 4;
        float4 b4 = *(const float4*)&bq[cc];
        q0[cc] = s.x + b4.x; q0[cc + 1] = s.y + b4.y;
        q0[cc + 2] = s.z + b4.z; q0[cc + 3] = s.w + b4.w;
    }
}

// ---------------------------------------------------------------------------
// wkq[k][h] = (Wk[k, h*48..+48] . q0[h*48..+48]) / sqrt(48); +16 bias terms.
// grid 48 x 256: thread = (kl = t>>4, h = t&15).
__global__ __launch_bounds__(256) void wkq_prep(
    const float* __restrict__ Wk, const float* __restrict__ bk,
    const float* __restrict__ q0, float* __restrict__ wkqc)
{
    __shared__ float qs[768];
    int t = threadIdx.x;
    qs[t] = q0[t]; qs[t + 256] = q0[t + 256]; qs[t + 512] = q0[t + 512];
    __syncthreads();
    const float invs = 0.14433756729740643f;  // 1/sqrt(48)
    int kl = t >> 4, h = t & 15;
    int k = blockIdx.x * 16 + kl;
    const float* wr = Wk + (size_t)k * 768 + h * 48;
    const float* qh = qs + h * 48;
    float a = 0.f;
#pragma unroll
    for (int d = 0; d < 48; d += 4) {
        float4 w = *(const float4*)&wr[d];
        a += w.x * qh[d] + w.y * qh[d + 1] + w.z * qh[d + 2] + w.w * qh[d + 3];
    }
    wkqc[k * 16 + h] = a * invs;
    if (blockIdx.x == 0 && t < 16) {
        float c = 0.f;
        for (int d = 0; d < 48; ++d) c += bk[t * 48 + d] * qs[t * 48 + d];
        wkqc[12288 + t] = c * invs;
    }
}

// ---------------------------------------------------------------------------
// Pass 1: fused LN1 + 16-head score GEMV for all 8192 rows.
// grid 512 (16 rows/block). Saves (mean, rden) per row for pass 2.
__global__ __launch_bounds__(256) void ln_scores(
    const float* __restrict__ tf, const float* __restrict__ clsT,
    const float* __restrict__ ga, const float* __restrict__ gb,
    const float* __restrict__ wkqc, float* __restrict__ sc,
    float2* __restrict__ stats)
{
    __shared__ float wk[768 * 17];   // [d][17], cols 0..15 used (52.2 KB)
    __shared__ float xs[768];
    __shared__ float part[4][16];
    __shared__ float red[4];
    __shared__ float c16[16];
    int t = threadIdx.x;
    for (int i = t; i < 12288; i += 256) wk[(i >> 4) * 17 + (i & 15)] = wkqc[i];
    if (t < 16) c16[t] = wkqc[12288 + t];
    __syncthreads();

    int r0 = blockIdx.x * 16;
    int lane = t & 63, w = t >> 6;
    int hh = t & 15, dg = t >> 4;     // dot-phase role
    float ga0 = ga[t], ga1 = ga[t + 256], ga2 = ga[t + 512];
    float gb0 = gb[t], gb1 = gb[t + 256], gb2 = gb[t + 512];

    for (int r = 0; r < 16; ++r) {
        int row = r0 + r;
        int b = row >> 10, j = row & 1023;
        const float* src = j ? (tf + ((size_t)b * 1023 + (j - 1)) * 768) : clsT;
        float x0 = src[t], x1 = src[t + 256], x2 = src[t + 512];
        float mean = bsum256(x0 + x1 + x2, red) * (1.0f / 768.0f);
        float d0 = x0 - mean, d1 = x1 - mean, d2 = x2 - mean;
        float var = bsum256(d0 * d0 + d1 * d1 + d2 * d2, red) * (1.0f / 767.0f);
        float rden = 1.0f / (sqrtf(var) + 1e-6f);
        xs[t]       = (ga0 * d0) * rden + gb0;
        xs[t + 256] = (ga1 * d1) * rden + gb1;
        xs[t + 512] = (ga2 * d2) * rden + gb2;
        if (t == 0) stats[row] = make_float2(mean, rden);
        __syncthreads();
        // dot: thread (hh, dg) covers d = dg*48 .. +48 for head hh
        float a = 0.f;
        int dbase = dg * 48;
#pragma unroll
        for (int i = 0; i < 48; ++i) a = fmaf(xs[dbase + i], wk[(dbase + i) * 17 + hh], a);
        a += __shfl_xor(a, 16);
        a += __shfl_xor(a, 32);
        if ((lane >> 4) == 0) part[w][hh] = a;
        __syncthreads();
        if (t < 16) {
            float sv = part[0][t] + part[1][t] + part[2][t] + part[3][t] + c16[t];
            sc[(((size_t)b * 16 + t) << 10) + j] = sv;
        }
        // next row's first bsum barrier protects xs/part reuse
    }
}

// ---------------------------------------------------------------------------
// softmax over j (1024) per (b,h). grid 128.
__global__ __launch_bounds__(256) void softmax_k(
    const float* __restrict__ sc, float* __restrict__ p)
{
    __shared__ float red[4];
    int bh = blockIdx.x, t = threadIdx.x;
    const float4* s4 = (const float4*)(sc + ((size_t)bh << 10));
    float4 v = s4[t];
    float m = fmaxf(fmaxf(v.x, v.y), fmaxf(v.z, v.w));
    float M = bmax256(m, red);
    float e0 = expf(v.x - M), e1 = expf(v.y - M), e2 = expf(v.z - M), e3 = expf(v.w - M);
    float Z = bsum256(e0 + e1 + e2 + e3, red);
    float4 o; o.x = e0 / Z; o.y = e1 / Z; o.z = e2 / Z; o.w = e3 / Z;
    ((float4*)(p + ((size_t)bh << 10)))[t] = o;
}

// ---------------------------------------------------------------------------
// Pass 2: partial u[b,h,:] = Σ_j p[b,h,j]*Xln[b,j,:] over a 64-row j-chunk.
// grid 128 = (b 8) x (jc 16). LN recomputed from saved stats.
__global__ __launch_bounds__(256) void upart_k(
    const float* __restrict__ tf, const float* __restrict__ clsT,
    const float2* __restrict__ stats, const float* __restrict__ ga,
    const float* __restrict__ gb, const float* __restrict__ p,
    float* __restrict__ up)
{
    __shared__ float ps[16][64];
    int b = blockIdx.x & 7, jc = blockIdx.x >> 3;
    int t = threadIdx.x;
    {   // stage p[16][64] slice
        int h = t >> 4, j4 = (t & 15) * 4;
        const float* prow = p + (((size_t)b * 16 + h) << 10) + jc * 64 + j4;
        float4 pv = *(const float4*)prow;
        ps[h][j4] = pv.x; ps[h][j4 + 1] = pv.y; ps[h][j4 + 2] = pv.z; ps[h][j4 + 3] = pv.w;
    }
    __syncthreads();
    float ga0 = ga[t], ga1 = ga[t + 256], ga2 = ga[t + 512];
    float gb0 = gb[t], gb1 = gb[t + 256], gb2 = gb[t + 512];
    float acc[16][3];
#pragma unroll
    for (int h = 0; h < 16; ++h) { acc[h][0] = 0.f; acc[h][1] = 0.f; acc[h][2] = 0.f; }

    for (int jj = 0; jj < 64; ++jj) {
        int j = jc * 64 + jj;
        const float* src = j ? (tf + ((size_t)b * 1023 + (j - 1)) * 768) : clsT;
        float2 st = stats[(b << 10) + j];
        float x0 = src[t], x1 = src[t + 256], x2 = src[t + 512];
        float xl0 = (ga0 * (x0 - st.x)) * st.y + gb0;
        float xl1 = (ga1 * (x1 - st.x)) * st.y + gb1;
        float xl2 = (ga2 * (x2 - st.x)) * st.y + gb2;
#pragma unroll
        for (int h = 0; h < 16; ++h) {
            float ph = ps[h][jj];
            acc[h][0] = fmaf(ph, xl0, acc[h][0]);
            acc[h][1] = fmaf(ph, xl1, acc[h][1]);
            acc[h][2] = fmaf(ph, xl2, acc[h][2]);
        }
    }
    float* o = up + (((size_t)b * 16 + jc) * 16) * 768;
#pragma unroll
    for (int h = 0; h < 16; ++h) {
        o[h * 768 + t] = acc[h][0];
        o[h * 768 + t + 256] = acc[h][1];
        o[h * 768 + t + 512] = acc[h][2];
    }
}

// ---------------------------------------------------------------------------
// reduce 16 u-partials, then o0 head-slice = u @ Wv[:,h*48..+48] + bv.
// grid (16 h, 8 b).
__global__ __launch_bounds__(256) void o0_k(
    const float* __restrict__ up, const float* __restrict__ Wv,
    const float* __restrict__ bv, float* __restrict__ o0)
{
    __shared__ float us[768];
    __shared__ float part[4][64];
    int h = blockIdx.x, b = blockIdx.y, t = threadIdx.x;
    float s0 = 0.f, s1 = 0.f, s2 = 0.f;
#pragma unroll
    for (int jc = 0; jc < 16; ++jc) {
        const float* q = up + (((size_t)b * 16 + jc) * 16 + h) * 768;
        s0 += q[t]; s1 += q[t + 256]; s2 += q[t + 512];
    }
    us[t] = s0; us[t + 256] = s1; us[t + 512] = s2;
    __syncthreads();
    int dd = t & 63, kg = t >> 6;    // 4 groups x 192 k
    float a = 0.f;
    if (dd < 48) {
#pragma unroll 8
        for (int i = 0; i < 192; ++i) {
            int k = kg * 192 + i;
            a = fmaf(us[k], Wv[(size_t)k * 768 + h * 48 + dd], a);
        }
    }
    part[kg][dd] = a;
    __syncthreads();
    if (t < 48)
        o0[(size_t)b * 768 + h * 48 + t] =
            part[0][t] + part[1][t] + part[2][t] + part[3][t] + bv[h * 48 + t];
}

// ---------------------------------------------------------------------------
// x2 = clsT + o0 @ Wo + bo. grid (12, 8).
__global__ __launch_bounds__(256) void x2_k(
    const float* __restrict__ o0, const float* __restrict__ Wo,
    const float* __restrict__ bo, const float* __restrict__ clsT,
    float* __restrict__ x2w)
{
    __shared__ float ys[768];
    __shared__ float4 part[16][17];
    int b = blockIdx.y, t = threadIdx.x;
    const float* xr = o0 + (size_t)b * 768;
    ys[t] = xr[t]; ys[t + 256] = xr[t + 256]; ys[t + 512] = xr[t + 512];
    __syncthreads();
    int c = blockIdx.x * 64 + (t & 15) * 4;
    int kq = t >> 4;
    float4 acc = {0.f, 0.f, 0.f, 0.f};
#pragma unroll 8
    for (int i = 0; i < 48; ++i) {
        int k = kq * 48 + i;
        float4 w = *(const float4*)&Wo[(size_t)k * 768 + c];
        float y = ys[k];
        acc.x = fmaf(y, w.x, acc.x); acc.y = fmaf(y, w.y, acc.y);
        acc.z = fmaf(y, w.z, acc.z); acc.w = fmaf(y, w.w, acc.w);
    }
    part[kq][t & 15] = acc;
    __syncthreads();
    if (t < 16) {
        float4 s = {0.f, 0.f, 0.f, 0.f};
#pragma unroll
        for (int i = 0; i < 16; ++i) {
            float4 v = part[i][t];
            s.x += v.x; s.y += v.y; s.z += v.z; s.w += v.w;
        }
        int cc = blockIdx.x * 64 + t * 4;
        float4 b4 = *(const float4*)&bo[cc];
        float4 r4 = *(const float4*)&clsT[cc];
        float* o = x2w + (size_t)b * 768 + cc;
        o[0] = s.x + b4.x + r4.x; o[1] = s.y + b4.y + r4.y;
        o[2] = s.z + b4.z + r4.z; o[3] = s.w + b4.w + r4.w;
    }
}

// ---------------------------------------------------------------------------
// f1 = relu(h @ W1 + b1). grid (24, 8): 128 cols/block, 8 k-groups x 96.
__global__ __launch_bounds__(256) void f1_k(
    const float* __restrict__ hw, const float* __restrict__ W1,
    const float* __restrict__ b1, float* __restrict__ f1w)
{
    __shared__ float ys[768];
    __shared__ float4 part[8][33];
    int b = blockIdx.y, t = threadIdx.x;
    const float* xr = hw + (size_t)b * 768;
    ys[t] = xr[t]; ys[t + 256] = xr[t + 256]; ys[t + 512] = xr[t + 512];
    __syncthreads();
    int c = blockIdx.x * 128 + (t & 31) * 4;
    int kq = t >> 5;
    float4 acc = {0.f, 0.f, 0.f, 0.f};
#pragma unroll 8
    for (int i = 0; i < 96; ++i) {
        int k = kq * 96 + i;
        float4 w = *(const float4*)&W1[(size_t)k * 3072 + c];
        float y = ys[k];
        acc.x = fmaf(y, w.x, acc.x); acc.y = fmaf(y, w.y, acc.y);
        acc.z = fmaf(y, w.z, acc.z); acc.w = fmaf(y, w.w, acc.w);
    }
    part[kq][t & 31] = acc;
    __syncthreads();
    if (t < 32) {
        float4 s = {0.f, 0.f, 0.f, 0.f};
#pragma unroll
        for (int i = 0; i < 8; ++i) {
            float4 v = part[i][t];
            s.x += v.x; s.y += v.y; s.z += v.z; s.w += v.w;
        }
        int cc = blockIdx.x * 128 + t * 4;
        float4 b4 = *(const float4*)&b1[cc];
        float* o = f1w + (size_t)b * 3072 + cc;
        o[0] = fmaxf(s.x + b4.x, 0.f); o[1] = fmaxf(s.y + b4.y, 0.f);
        o[2] = fmaxf(s.z + b4.z, 0.f); o[3] = fmaxf(s.w + b4.w, 0.f);
    }
}

// ---------------------------------------------------------------------------
// x3 = x2 + f1 @ W2 + b2. grid (12, 8): 64 cols/block, 16 k-groups x 192.
__global__ __launch_bounds__(256) void x3_k(
    const float* __restrict__ f1w, const float* __restrict__ W2,
    const float* __restrict__ b2, const float* __restrict__ x2w,
    float* __restrict__ x3w)
{
    __shared__ float ys[3072];
    __shared__ float4 part[16][17];
    int b = blockIdx.y, t = threadIdx.x;
    const float* xr = f1w + (size_t)b * 3072;
    for (int i = t; i < 3072; i += 256) ys[i] = xr[i];
    __syncthreads();
    int c = blockIdx.x * 64 + (t & 15) * 4;
    int kq = t >> 4;
    float4 acc = {0.f, 0.f, 0.f, 0.f};
#pragma unroll 8
    for (int i = 0; i < 192; ++i) {
        int k = kq * 192 + i;
        float4 w = *(const float4*)&W2[(size_t)k * 768 + c];
        float y = ys[k];
        acc.x = fmaf(y, w.x, acc.x); acc.y = fmaf(y, w.y, acc.y);
        acc.z = fmaf(y, w.z, acc.z); acc.w = fmaf(y, w.w, acc.w);
    }
    part[kq][t & 15] = acc;
    __syncthreads();
    if (t < 16) {
        float4 s = {0.f, 0.f, 0.f, 0.f};
#pragma unroll
        for (int i = 0; i < 16; ++i) {
            float4 v = part[i][t];
            s.x += v.x; s.y += v.y; s.z += v.z; s.w += v.w;
        }
        int cc = blockIdx.x * 64 + t * 4;
        float4 b4 = *(const float4*)&b2[cc];
        const float* x2r = x2w + (size_t)b * 768 + cc;
        float* o = x3w + (size_t)b * 768 + cc;
        o[0] = x2r[0] + s.x + b4.x; o[1] = x2r[1] + s.y + b4.y;
        o[2] = x2r[2] + s.z + b4.z; o[3] = x2r[3] + s.w + b4.w;
    }
}

// ---------------------------------------------------------------------------
// Head logits: pool softmax, class logits, entropy -> adjusted_k, stable
// top-k rank. One block per batch. Writes top[8][100] + kk[8] to ws; the
// bulk gather runs in gather_k (800 blocks) to avoid the round-3 latency trap.
__global__ __launch_bounds__(256) void head_logits(
    const float* __restrict__ clsw, const float* __restrict__ Wpool,
    const float* __restrict__ bpool, const float* __restrict__ Wcls,
    const float* __restrict__ bcls, float* __restrict__ out,
    int* __restrict__ topw, int* __restrict__ kkw)
{
    __shared__ float sC[768];
    __shared__ double sP[100];
    __shared__ double sC7[7];
    __shared__ double partP[2][100];
    __shared__ double partC[8][7];
    int b = blockIdx.x, t = threadIdx.x;
    for (int i = t; i < 768; i += 256) sC[i] = clsw[(size_t)b * 768 + i];
    __syncthreads();
    if (t < 200) {
        int kg = (t >= 100) ? 1 : 0;
        int c = t - kg * 100;
        double a = 0.0;
#pragma unroll 8
        for (int i = 0; i < 384; ++i) {
            int k = kg * 384 + i;
            a = fma((double)sC[k], (double)Wpool[k * 100 + c], a);
        }
        partP[kg][c] = a;
    } else {                       // t in [200, 256): exactly 56 threads
        int idx = t - 200;         // 0..55
        int kg = idx / 7, c = idx - kg * 7;   // kg 0..7, c 0..6
        double a = 0.0;
#pragma unroll 8
        for (int i = 0; i < 96; ++i) {
            int k = kg * 96 + i;
            a = fma((double)sC[k], (double)Wcls[k * 7 + c], a);
        }
        partC[kg][c] = a;
    }
    __syncthreads();
    if (t < 100) sP[t] = partP[0][t] + partP[1][t] + (double)bpool[t];
    if (t >= 128 && t < 135) {
        int c = t - 128;
        double a = (double)bcls[c];
#pragma unroll
        for (int kg = 0; kg < 8; ++kg) a += partC[kg][c];
        sC7[c] = a;
        out[OUT_CLS_OFF + b * 7 + c] = (float)a;
    }
    __syncthreads();
    double mx = sP[0];
    for (int j = 1; j < 100; ++j) mx = fmax(mx, sP[j]);
    double e = (t < 100) ? exp(sP[t] - mx) : 0.0;
    __syncthreads();
    if (t < 100) sP[t] = e;
    __syncthreads();
    double zs = 0.0;
    for (int j = 0; j < 100; ++j) zs += sP[j];
    __syncthreads();
    if (t < 100) sP[t] = e / zs;
    __syncthreads();
    if (t == 0) {
        double m7 = sC7[0];
        for (int j = 1; j < 7; ++j) m7 = fmax(m7, sC7[j]);
        double es[7]; double z = 0.0;
        for (int j = 0; j < 7; ++j) { es[j] = exp(sC7[j] - m7); z += es[j]; }
        double ent = 0.0;
        for (int j = 0; j < 7; ++j) { double pr = es[j] / z; ent -= pr * log(pr + 1e-9); }
        double ne = ent / log(7.0);
        int kk = (int)floor(1.0 + ne * 99.0);
        kkw[b] = kk < 1 ? 1 : (kk > 100 ? 100 : kk);
    }
    if (t < 100) {
        double pi = sP[t];
        int r = 0;
        for (int j = 0; j < 100; ++j) {
            double pj = sP[j];
            r += (pj > pi) || (pj == pi && j < t);
        }
        topw[b * 100 + r] = t;   // descending, stable (lower index first)
    }
}

// ---------------------------------------------------------------------------
// gather: out[b, r, :] = (r < kk[b]) ? pool[top[b][r], :] : 0.
// grid (100 r, 8 b), 192 threads x float4 = 768 floats. Fully coalesced.
__global__ __launch_bounds__(192) void gather_k(
    const float* __restrict__ pool, const int* __restrict__ topw,
    const int* __restrict__ kkw, float* __restrict__ out)
{
    int r = blockIdx.x, b = blockIdx.y, t = threadIdx.x;
    int idx = topw[b * 100 + r];
    bool keep = r < kkw[b];
    const float4* src = (const float4*)(pool + (size_t)idx * 768);
    float4* dst = (float4*)(out + (size_t)b * 76800 + (size_t)r * 768);
    float4 z = {0.f, 0.f, 0.f, 0.f};
    dst[t] = keep ? src[t] : z;
}

// ---------------------------------------------------------------------------
extern "C" void kernel_launch(void* const* d_in, const int* in_sizes, int n_in,
                              void* d_out, int out_size, void* d_ws, size_t ws_size,
                              hipStream_t stream) {
    (void)in_sizes; (void)n_in; (void)out_size; (void)ws_size;
    const float* tf    = (const float*)d_in[0];
    const float* pool  = (const float*)d_in[1];
    const float* clsT  = (const float*)d_in[2];
    const float* Wq    = (const float*)d_in[3];
    const float* bq    = (const float*)d_in[4];
    const float* Wk    = (const float*)d_in[5];
    const float* bk    = (const float*)d_in[6];
    const float* Wv    = (const float*)d_in[7];
    const float* bv    = (const float*)d_in[8];
    const float* Wo    = (const float*)d_in[9];
    const float* bo    = (const float*)d_in[10];
    const float* ln1a  = (const float*)d_in[11];
    const float* ln1b  = (const float*)d_in[12];
    const float* ln2a  = (const float*)d_in[13];
    const float* ln2b  = (const float*)d_in[14];
    const float* W1    = (const float*)d_in[15];
    const float* b1    = (const float*)d_in[16];
    const float* W2    = (const float*)d_in[17];
    const float* b2    = (const float*)d_in[18];
    const float* lnfa  = (const float*)d_in[19];
    const float* lnfb  = (const float*)d_in[20];
    const float* Wpool = (const float*)d_in[21];
    const float* bpool = (const float*)d_in[22];
    const float* Wcls  = (const float*)d_in[23];
    const float* bcls  = (const float*)d_in[24];
    float* out = (float*)d_out;
    char* ws = (char*)d_ws;

    float*  sc    = (float*)(ws + 0);          // 524,288 B (128 x 1024)
    float*  p     = (float*)(ws + 524288);     // 524,288
    float2* stats = (float2*)(ws + 1048576);   // 65,536
    float*  wkqc  = (float*)(ws + 1114112);    // 49,408 (12288 + 16, padded)
    float*  y0    = (float*)(ws + 1163520);    // 3,072
    float*  q0    = (float*)(ws + 1166592);    // 3,072
    float*  upart = (float*)(ws + 1169664);    // 6,291,456 (8 x 16 x 16 x 768)
    float*  o0    = (float*)(ws + 7461120);    // 24,576
    float*  x2w   = (float*)(ws + 7485696);    // 24,576
    float*  hw    = (float*)(ws + 7510272);    // 24,576
    float*  f1w   = (float*)(ws + 7534848);    // 98,304
    float*  x3w   = (float*)(ws + 7633152);    // 24,576
    float*  clsw  = (float*)(ws + 7657728);    // 24,576
    int*    topw  = (int*)(ws + 7682304);      // 3,200
    int*    kkw   = (int*)(ws + 7685504);      // 32   (total ~7.7 MB)

    ln_row<<<1, 256, 0, stream>>>(clsT, ln1a, ln1b, y0);
    q0_gemv<<<12, 256, 0, stream>>>(y0, Wq, bq, q0);
    wkq_prep<<<48, 256, 0, stream>>>(Wk, bk, q0, wkqc);
    ln_scores<<<512, 256, 0, stream>>>(tf, clsT, ln1a, ln1b, wkqc, sc, stats);
    softmax_k<<<128, 256, 0, stream>>>(sc, p);
    upart_k<<<128, 256, 0, stream>>>(tf, clsT, stats, ln1a, ln1b, p, upart);
    o0_k<<<dim3(16, 8), 256, 0, stream>>>(upart, Wv, bv, o0);
    x2_k<<<dim3(12, 8), 256, 0, stream>>>(o0, Wo, bo, clsT, x2w);
    ln_row<<<8, 256, 0, stream>>>(x2w, ln2a, ln2b, hw);
    f1_k<<<dim3(24, 8), 256, 0, stream>>>(hw, W1, b1, f1w);
    x3_k<<<dim3(12, 8), 256, 0, stream>>>(f1w, W2, b2, x2w, x3w);
    ln_row<<<8, 256, 0, stream>>>(x3w, lnfa, lnfb, clsw);
    head_logits<<<8, 256, 0, stream>>>(clsw, Wpool, bpool, Wcls, bcls, out, topw, kkw);
    gather_k<<<dim3(100, 8), 192, 0, stream>>>(pool, topw, kkw, out);
}

// Round 5
// 136.221 us; speedup vs baseline: 3.1609x; 1.1355x over previous
//
#include <hip/hip_runtime.h>

// ---------------------------------------------------------------------------
// PromptSelector — collapsed-algebra version.
// Outputs depend only on the CLS row. K/V GEMMs are algebraically folded:
//   scores[b,h,j] = Xln[b,j,:] . wkq[:,h] + c[h]     (wkq = Wk_h @ q0_h /√48)
//   o[b,h,:]      = (Σ_j p_j Xln[b,j,:]) @ Wv_h + bv_h
// Two streaming passes over X (25 MB each) + small fp32 GEMVs. No MFMA.
// Round 5: head GEMV k-split across 64 blocks (round-4's 47 µs was 8 blocks
// latency-starved); LN fused into q0_gemv / f1_k / logits_part (3 fewer
// serial launches). Head decisions stay in double, fixed summation order.
// ---------------------------------------------------------------------------

#define OUT_CLS_OFF 614400   // 8*100*768

// block-wide (256 thr) sum reduce; red must hold >=4 floats
__device__ __forceinline__ float bsum256(float v, float* red) {
    int lane = threadIdx.x & 63, w = threadIdx.x >> 6;
#pragma unroll
    for (int off = 1; off < 64; off <<= 1) v += __shfl_xor(v, off);
    __syncthreads();
    if (lane == 0) red[w] = v;
    __syncthreads();
    return red[0] + red[1] + red[2] + red[3];
}
__device__ __forceinline__ float bmax256(float v, float* red) {
    int lane = threadIdx.x & 63, w = threadIdx.x >> 6;
#pragma unroll
    for (int off = 1; off < 64; off <<= 1) v = fmaxf(v, __shfl_xor(v, off));
    __syncthreads();
    if (lane == 0) red[w] = v;
    __syncthreads();
    return fmaxf(fmaxf(red[0], red[1]), fmaxf(red[2], red[3]));
}

// ---------------------------------------------------------------------------
// q0 = LN1(cls) @ Wq + bq, LN fused (each of 12 blocks recomputes cls LN).
// grid 12, block 256: 64 cols/block (16 thr x float4), 16 k-groups x 48.
__global__ __launch_bounds__(256) void q0_gemv(
    const float* __restrict__ clsT, const float* __restrict__ ga,
    const float* __restrict__ gb, const float* __restrict__ Wq,
    const float* __restrict__ bq, float* __restrict__ q0)
{
    __shared__ float ys[768];
    __shared__ float red[4];
    __shared__ float4 part[16][17];
    int t = threadIdx.x;
    float a0 = clsT[t], a1 = clsT[t + 256], a2 = clsT[t + 512];
    float mean = bsum256(a0 + a1 + a2, red) * (1.0f / 768.0f);
    float d0 = a0 - mean, d1 = a1 - mean, d2 = a2 - mean;
    float var = bsum256(d0 * d0 + d1 * d1 + d2 * d2, red) * (1.0f / 767.0f);
    float den = sqrtf(var) + 1e-6f;
    ys[t]       = (ga[t] * d0) / den + gb[t];
    ys[t + 256] = (ga[t + 256] * d1) / den + gb[t + 256];
    ys[t + 512] = (ga[t + 512] * d2) / den + gb[t + 512];
    __syncthreads();
    int c = blockIdx.x * 64 + (t & 15) * 4;
    int kq = t >> 4;
    float4 acc = {0.f, 0.f, 0.f, 0.f};
#pragma unroll 8
    for (int i = 0; i < 48; ++i) {
        int k = kq * 48 + i;
        float4 w = *(const float4*)&Wq[(size_t)k * 768 + c];
        float y = ys[k];
        acc.x = fmaf(y, w.x, acc.x); acc.y = fmaf(y, w.y, acc.y);
        acc.z = fmaf(y, w.z, acc.z); acc.w = fmaf(y, w.w, acc.w);
    }
    part[kq][t & 15] = acc;
    __syncthreads();
    if (t < 16) {
        float4 s = {0.f, 0.f, 0.f, 0.f};
#pragma unroll
        for (int i = 0; i < 16; ++i) {
            float4 v = part[i][t];
            s.x += v.x; s.y += v.y; s.z += v.z; s.w += v.w;
        }
        int cc = blockIdx.x * 64 + t * 4;
        float4 b4 = *(const float4*)&bq[cc];
        q0[cc] = s.x + b4.x; q0[cc + 1] = s.y + b4.y;
        q0[cc + 2] = s.z + b4.z; q0[cc + 3] = s.w + b4.w;
    }
}

// ---------------------------------------------------------------------------
// wkq[k][h] = (Wk[k, h*48..+48] . q0[h*48..+48]) / sqrt(48); +16 bias terms.
// grid 48 x 256: thread = (kl = t>>4, h = t&15).
__global__ __launch_bounds__(256) void wkq_prep(
    const float* __restrict__ Wk, const float* __restrict__ bk,
    const float* __restrict__ q0, float* __restrict__ wkqc)
{
    __shared__ float qs[768];
    int t = threadIdx.x;
    qs[t] = q0[t]; qs[t + 256] = q0[t + 256]; qs[t + 512] = q0[t + 512];
    __syncthreads();
    const float invs = 0.14433756729740643f;  // 1/sqrt(48)
    int kl = t >> 4, h = t & 15;
    int k = blockIdx.x * 16 + kl;
    const float* wr = Wk + (size_t)k * 768 + h * 48;
    const float* qh = qs + h * 48;
    float a = 0.f;
#pragma unroll
    for (int d = 0; d < 48; d += 4) {
        float4 w = *(const float4*)&wr[d];
        a += w.x * qh[d] + w.y * qh[d + 1] + w.z * qh[d + 2] + w.w * qh[d + 3];
    }
    wkqc[k * 16 + h] = a * invs;
    if (blockIdx.x == 0 && t < 16) {
        float c = 0.f;
        for (int d = 0; d < 48; ++d) c += bk[t * 48 + d] * qs[t * 48 + d];
        wkqc[12288 + t] = c * invs;
    }
}

// ---------------------------------------------------------------------------
// Pass 1: fused LN1 + 16-head score GEMV for all 8192 rows.
// grid 512 (16 rows/block). Saves (mean, rden) per row for pass 2.
__global__ __launch_bounds__(256) void ln_scores(
    const float* __restrict__ tf, const float* __restrict__ clsT,
    const float* __restrict__ ga, const float* __restrict__ gb,
    const float* __restrict__ wkqc, float* __restrict__ sc,
    float2* __restrict__ stats)
{
    __shared__ float wk[768 * 17];   // [d][17], cols 0..15 used (52.2 KB)
    __shared__ float xs[768];
    __shared__ float part[4][16];
    __shared__ float red[4];
    __shared__ float c16[16];
    int t = threadIdx.x;
    for (int i = t; i < 12288; i += 256) wk[(i >> 4) * 17 + (i & 15)] = wkqc[i];
    if (t < 16) c16[t] = wkqc[12288 + t];
    __syncthreads();

    int r0 = blockIdx.x * 16;
    int lane = t & 63, w = t >> 6;
    int hh = t & 15, dg = t >> 4;     // dot-phase role
    float ga0 = ga[t], ga1 = ga[t + 256], ga2 = ga[t + 512];
    float gb0 = gb[t], gb1 = gb[t + 256], gb2 = gb[t + 512];

    for (int r = 0; r < 16; ++r) {
        int row = r0 + r;
        int b = row >> 10, j = row & 1023;
        const float* src = j ? (tf + ((size_t)b * 1023 + (j - 1)) * 768) : clsT;
        float x0 = src[t], x1 = src[t + 256], x2 = src[t + 512];
        float mean = bsum256(x0 + x1 + x2, red) * (1.0f / 768.0f);
        float d0 = x0 - mean, d1 = x1 - mean, d2 = x2 - mean;
        float var = bsum256(d0 * d0 + d1 * d1 + d2 * d2, red) * (1.0f / 767.0f);
        float rden = 1.0f / (sqrtf(var) + 1e-6f);
        xs[t]       = (ga0 * d0) * rden + gb0;
        xs[t + 256] = (ga1 * d1) * rden + gb1;
        xs[t + 512] = (ga2 * d2) * rden + gb2;
        if (t == 0) stats[row] = make_float2(mean, rden);
        __syncthreads();
        // dot: thread (hh, dg) covers d = dg*48 .. +48 for head hh
        float a = 0.f;
        int dbase = dg * 48;
#pragma unroll
        for (int i = 0; i < 48; ++i) a = fmaf(xs[dbase + i], wk[(dbase + i) * 17 + hh], a);
        a += __shfl_xor(a, 16);
        a += __shfl_xor(a, 32);
        if ((lane >> 4) == 0) part[w][hh] = a;
        __syncthreads();
        if (t < 16) {
            float sv = part[0][t] + part[1][t] + part[2][t] + part[3][t] + c16[t];
            sc[(((size_t)b * 16 + t) << 10) + j] = sv;
        }
        // next row's first bsum barrier protects xs/part reuse
    }
}

// ---------------------------------------------------------------------------
// softmax over j (1024) per (b,h). grid 128.
__global__ __launch_bounds__(256) void softmax_k(
    const float* __restrict__ sc, float* __restrict__ p)
{
    __shared__ float red[4];
    int bh = blockIdx.x, t = threadIdx.x;
    const float4* s4 = (const float4*)(sc + ((size_t)bh << 10));
    float4 v = s4[t];
    float m = fmaxf(fmaxf(v.x, v.y), fmaxf(v.z, v.w));
    float M = bmax256(m, red);
    float e0 = expf(v.x - M), e1 = expf(v.y - M), e2 = expf(v.z - M), e3 = expf(v.w - M);
    float Z = bsum256(e0 + e1 + e2 + e3, red);
    float4 o; o.x = e0 / Z; o.y = e1 / Z; o.z = e2 / Z; o.w = e3 / Z;
    ((float4*)(p + ((size_t)bh << 10)))[t] = o;
}

// ---------------------------------------------------------------------------
// Pass 2: partial u[b,h,:] = Σ_j p[b,h,j]*Xln[b,j,:] over a 64-row j-chunk.
// grid 128 = (b 8) x (jc 16). LN recomputed from saved stats.
__global__ __launch_bounds__(256) void upart_k(
    const float* __restrict__ tf, const float* __restrict__ clsT,
    const float2* __restrict__ stats, const float* __restrict__ ga,
    const float* __restrict__ gb, const float* __restrict__ p,
    float* __restrict__ up)
{
    __shared__ float ps[16][64];
    int b = blockIdx.x & 7, jc = blockIdx.x >> 3;
    int t = threadIdx.x;
    {   // stage p[16][64] slice
        int h = t >> 4, j4 = (t & 15) * 4;
        const float* prow = p + (((size_t)b * 16 + h) << 10) + jc * 64 + j4;
        float4 pv = *(const float4*)prow;
        ps[h][j4] = pv.x; ps[h][j4 + 1] = pv.y; ps[h][j4 + 2] = pv.z; ps[h][j4 + 3] = pv.w;
    }
    __syncthreads();
    float ga0 = ga[t], ga1 = ga[t + 256], ga2 = ga[t + 512];
    float gb0 = gb[t], gb1 = gb[t + 256], gb2 = gb[t + 512];
    float acc[16][3];
#pragma unroll
    for (int h = 0; h < 16; ++h) { acc[h][0] = 0.f; acc[h][1] = 0.f; acc[h][2] = 0.f; }

    for (int jj = 0; jj < 64; ++jj) {
        int j = jc * 64 + jj;
        const float* src = j ? (tf + ((size_t)b * 1023 + (j - 1)) * 768) : clsT;
        float2 st = stats[(b << 10) + j];
        float x0 = src[t], x1 = src[t + 256], x2 = src[t + 512];
        float xl0 = (ga0 * (x0 - st.x)) * st.y + gb0;
        float xl1 = (ga1 * (x1 - st.x)) * st.y + gb1;
        float xl2 = (ga2 * (x2 - st.x)) * st.y + gb2;
#pragma unroll
        for (int h = 0; h < 16; ++h) {
            float ph = ps[h][jj];
            acc[h][0] = fmaf(ph, xl0, acc[h][0]);
            acc[h][1] = fmaf(ph, xl1, acc[h][1]);
            acc[h][2] = fmaf(ph, xl2, acc[h][2]);
        }
    }
    float* o = up + (((size_t)b * 16 + jc) * 16) * 768;
#pragma unroll
    for (int h = 0; h < 16; ++h) {
        o[h * 768 + t] = acc[h][0];
        o[h * 768 + t + 256] = acc[h][1];
        o[h * 768 + t + 512] = acc[h][2];
    }
}

// ---------------------------------------------------------------------------
// reduce 16 u-partials, then o0 head-slice = u @ Wv[:,h*48..+48] + bv.
// grid (16 h, 8 b).
__global__ __launch_bounds__(256) void o0_k(
    const float* __restrict__ up, const float* __restrict__ Wv,
    const float* __restrict__ bv, float* __restrict__ o0)
{
    __shared__ float us[768];
    __shared__ float part[4][64];
    int h = blockIdx.x, b = blockIdx.y, t = threadIdx.x;
    float s0 = 0.f, s1 = 0.f, s2 = 0.f;
#pragma unroll
    for (int jc = 0; jc < 16; ++jc) {
        const float* q = up + (((size_t)b * 16 + jc) * 16 + h) * 768;
        s0 += q[t]; s1 += q[t + 256]; s2 += q[t + 512];
    }
    us[t] = s0; us[t + 256] = s1; us[t + 512] = s2;
    __syncthreads();
    int dd = t & 63, kg = t >> 6;    // 4 groups x 192 k
    float a = 0.f;
    if (dd < 48) {
#pragma unroll 8
        for (int i = 0; i < 192; ++i) {
            int k = kg * 192 + i;
            a = fmaf(us[k], Wv[(size_t)k * 768 + h * 48 + dd], a);
        }
    }
    part[kg][dd] = a;
    __syncthreads();
    if (t < 48)
        o0[(size_t)b * 768 + h * 48 + t] =
            part[0][t] + part[1][t] + part[2][t] + part[3][t] + bv[h * 48 + t];
}

// ---------------------------------------------------------------------------
// x2 = clsT + o0 @ Wo + bo. grid (12, 8).
__global__ __launch_bounds__(256) void x2_k(
    const float* __restrict__ o0, const float* __restrict__ Wo,
    const float* __restrict__ bo, const float* __restrict__ clsT,
    float* __restrict__ x2w)
{
    __shared__ float ys[768];
    __shared__ float4 part[16][17];
    int b = blockIdx.y, t = threadIdx.x;
    const float* xr = o0 + (size_t)b * 768;
    ys[t] = xr[t]; ys[t + 256] = xr[t + 256]; ys[t + 512] = xr[t + 512];
    __syncthreads();
    int c = blockIdx.x * 64 + (t & 15) * 4;
    int kq = t >> 4;
    float4 acc = {0.f, 0.f, 0.f, 0.f};
#pragma unroll 8
    for (int i = 0; i < 48; ++i) {
        int k = kq * 48 + i;
        float4 w = *(const float4*)&Wo[(size_t)k * 768 + c];
        float y = ys[k];
        acc.x = fmaf(y, w.x, acc.x); acc.y = fmaf(y, w.y, acc.y);
        acc.z = fmaf(y, w.z, acc.z); acc.w = fmaf(y, w.w, acc.w);
    }
    part[kq][t & 15] = acc;
    __syncthreads();
    if (t < 16) {
        float4 s = {0.f, 0.f, 0.f, 0.f};
#pragma unroll
        for (int i = 0; i < 16; ++i) {
            float4 v = part[i][t];
            s.x += v.x; s.y += v.y; s.z += v.z; s.w += v.w;
        }
        int cc = blockIdx.x * 64 + t * 4;
        float4 b4 = *(const float4*)&bo[cc];
        float4 r4 = *(const float4*)&clsT[cc];
        float* o = x2w + (size_t)b * 768 + cc;
        o[0] = s.x + b4.x + r4.x; o[1] = s.y + b4.y + r4.y;
        o[2] = s.z + b4.z + r4.z; o[3] = s.w + b4.w + r4.w;
    }
}

// ---------------------------------------------------------------------------
// f1 = relu(LN2(x2) @ W1 + b1), LN fused (each block recomputes row LN).
// grid (24, 8): 128 cols/block, 8 k-groups x 96.
__global__ __launch_bounds__(256) void f1_k(
    const float* __restrict__ x2w, const float* __restrict__ ga,
    const float* __restrict__ gb, const float* __restrict__ W1,
    const float* __restrict__ b1, float* __restrict__ f1w)
{
    __shared__ float ys[768];
    __shared__ float red[4];
    __shared__ float4 part[8][33];
    int b = blockIdx.y, t = threadIdx.x;
    const float* xr = x2w + (size_t)b * 768;
    float a0 = xr[t], a1 = xr[t + 256], a2 = xr[t + 512];
    float mean = bsum256(a0 + a1 + a2, red) * (1.0f / 768.0f);
    float d0 = a0 - mean, d1 = a1 - mean, d2 = a2 - mean;
    float var = bsum256(d0 * d0 + d1 * d1 + d2 * d2, red) * (1.0f / 767.0f);
    float den = sqrtf(var) + 1e-6f;
    ys[t]       = (ga[t] * d0) / den + gb[t];
    ys[t + 256] = (ga[t + 256] * d1) / den + gb[t + 256];
    ys[t + 512] = (ga[t + 512] * d2) / den + gb[t + 512];
    __syncthreads();
    int c = blockIdx.x * 128 + (t & 31) * 4;
    int kq = t >> 5;
    float4 acc = {0.f, 0.f, 0.f, 0.f};
#pragma unroll 8
    for (int i = 0; i < 96; ++i) {
        int k = kq * 96 + i;
        float4 w = *(const float4*)&W1[(size_t)k * 3072 + c];
        float y = ys[k];
        acc.x = fmaf(y, w.x, acc.x); acc.y = fmaf(y, w.y, acc.y);
        acc.z = fmaf(y, w.z, acc.z); acc.w = fmaf(y, w.w, acc.w);
    }
    part[kq][t & 31] = acc;
    __syncthreads();
    if (t < 32) {
        float4 s = {0.f, 0.f, 0.f, 0.f};
#pragma unroll
        for (int i = 0; i < 8; ++i) {
            float4 v = part[i][t];
            s.x += v.x; s.y += v.y; s.z += v.z; s.w += v.w;
        }
        int cc = blockIdx.x * 128 + t * 4;
        float4 b4 = *(const float4*)&b1[cc];
        float* o = f1w + (size_t)b * 3072 + cc;
        o[0] = fmaxf(s.x + b4.x, 0.f); o[1] = fmaxf(s.y + b4.y, 0.f);
        o[2] = fmaxf(s.z + b4.z, 0.f); o[3] = fmaxf(s.w + b4.w, 0.f);
    }
}

// ---------------------------------------------------------------------------
// x3 = x2 + f1 @ W2 + b2. grid (12, 8): 64 cols/block, 16 k-groups x 192.
__global__ __launch_bounds__(256) void x3_k(
    const float* __restrict__ f1w, const float* __restrict__ W2,
    const float* __restrict__ b2, const float* __restrict__ x2w,
    float* __restrict__ x3w)
{
    __shared__ float ys[3072];
    __shared__ float4 part[16][17];
    int b = blockIdx.y, t = threadIdx.x;
    const float* xr = f1w + (size_t)b * 3072;
    for (int i = t; i < 3072; i += 256) ys[i] = xr[i];
    __syncthreads();
    int c = blockIdx.x * 64 + (t & 15) * 4;
    int kq = t >> 4;
    float4 acc = {0.f, 0.f, 0.f, 0.f};
#pragma unroll 8
    for (int i = 0; i < 192; ++i) {
        int k = kq * 192 + i;
        float4 w = *(const float4*)&W2[(size_t)k * 768 + c];
        float y = ys[k];
        acc.x = fmaf(y, w.x, acc.x); acc.y = fmaf(y, w.y, acc.y);
        acc.z = fmaf(y, w.z, acc.z); acc.w = fmaf(y, w.w, acc.w);
    }
    part[kq][t & 15] = acc;
    __syncthreads();
    if (t < 16) {
        float4 s = {0.f, 0.f, 0.f, 0.f};
#pragma unroll
        for (int i = 0; i < 16; ++i) {
            float4 v = part[i][t];
            s.x += v.x; s.y += v.y; s.z += v.z; s.w += v.w;
        }
        int cc = blockIdx.x * 64 + t * 4;
        float4 b4 = *(const float4*)&b2[cc];
        const float* x2r = x2w + (size_t)b * 768 + cc;
        float* o = x3w + (size_t)b * 768 + cc;
        o[0] = x2r[0] + s.x + b4.x; o[1] = x2r[1] + s.y + b4.y;
        o[2] = x2r[2] + s.z + b4.z; o[3] = x2r[3] + s.w + b4.w;
    }
}

// ---------------------------------------------------------------------------
// Head logits, k-split: block (kg, b) computes double partials over k-chunk
// kg*96..+96 for 100 pool cols + 7 class cols. LNf fused (redundant per
// block). lp[b][kg][112] doubles.
__global__ __launch_bounds__(256) void logits_part(
    const float* __restrict__ x3w, const float* __restrict__ ga,
    const float* __restrict__ gb, const float* __restrict__ Wpool,
    const float* __restrict__ Wcls, double* __restrict__ lp)
{
    __shared__ float ys[768];
    __shared__ float red[4];
    int kg = blockIdx.x, b = blockIdx.y, t = threadIdx.x;
    const float* xr = x3w + (size_t)b * 768;
    float a0 = xr[t], a1 = xr[t + 256], a2 = xr[t + 512];
    float mean = bsum256(a0 + a1 + a2, red) * (1.0f / 768.0f);
    float d0 = a0 - mean, d1 = a1 - mean, d2 = a2 - mean;
    float var = bsum256(d0 * d0 + d1 * d1 + d2 * d2, red) * (1.0f / 767.0f);
    float den = sqrtf(var) + 1e-6f;
    ys[t]       = (ga[t] * d0) / den + gb[t];
    ys[t + 256] = (ga[t + 256] * d1) / den + gb[t + 256];
    ys[t + 512] = (ga[t + 512] * d2) / den + gb[t + 512];
    __syncthreads();
    int kbase = kg * 96;
    if (t < 100) {
        double a = 0.0;
#pragma unroll 8
        for (int i = 0; i < 96; ++i) {
            int k = kbase + i;
            a = fma((double)ys[k], (double)Wpool[k * 100 + t], a);
        }
        lp[((size_t)b * 8 + kg) * 112 + t] = a;
    } else if (t < 107) {
        int c = t - 100;
        double a = 0.0;
#pragma unroll 8
        for (int i = 0; i < 96; ++i) {
            int k = kbase + i;
            a = fma((double)ys[k], (double)Wcls[k * 7 + c], a);
        }
        lp[((size_t)b * 8 + kg) * 112 + t] = a;
    }
}

// ---------------------------------------------------------------------------
// Head decide: sum 8 partials (fixed order -> deterministic), pool softmax,
// class logits out, entropy -> adjusted_k, stable descending rank.
// grid 8, block 128. All discrete-feeding math in double.
__global__ __launch_bounds__(128) void head_decide(
    const double* __restrict__ lp, const float* __restrict__ bpool,
    const float* __restrict__ bcls, float* __restrict__ out,
    int* __restrict__ topw, int* __restrict__ kkw)
{
    __shared__ double sP[100];
    __shared__ double sC7[7];
    int b = blockIdx.x, t = threadIdx.x;
    if (t < 107) {
        double a = (t < 100) ? (double)bpool[t] : (double)bcls[t - 100];
#pragma unroll
        for (int kg = 0; kg < 8; ++kg) a += lp[((size_t)b * 8 + kg) * 112 + t];
        if (t < 100) sP[t] = a;
        else {
            sC7[t - 100] = a;
            out[OUT_CLS_OFF + b * 7 + (t - 100)] = (float)a;
        }
    }
    __syncthreads();
    double mx = sP[0];
    for (int j = 1; j < 100; ++j) mx = fmax(mx, sP[j]);
    double e = (t < 100) ? exp(sP[t] - mx) : 0.0;
    __syncthreads();
    if (t < 100) sP[t] = e;
    __syncthreads();
    double zs = 0.0;
    for (int j = 0; j < 100; ++j) zs += sP[j];
    __syncthreads();
    if (t < 100) sP[t] = e / zs;
    __syncthreads();
    if (t == 0) {
        double m7 = sC7[0];
        for (int j = 1; j < 7; ++j) m7 = fmax(m7, sC7[j]);
        double es[7]; double z = 0.0;
        for (int j = 0; j < 7; ++j) { es[j] = exp(sC7[j] - m7); z += es[j]; }
        double ent = 0.0;
        for (int j = 0; j < 7; ++j) { double pr = es[j] / z; ent -= pr * log(pr + 1e-9); }
        double ne = ent / log(7.0);
        int kk = (int)floor(1.0 + ne * 99.0);
        kkw[b] = kk < 1 ? 1 : (kk > 100 ? 100 : kk);
    }
    if (t < 100) {
        double pi = sP[t];
        int r = 0;
        for (int j = 0; j < 100; ++j) {
            double pj = sP[j];
            r += (pj > pi) || (pj == pi && j < t);
        }
        topw[b * 100 + r] = t;   // descending, stable (lower index first)
    }
}

// ---------------------------------------------------------------------------
// gather: out[b, r, :] = (r < kk[b]) ? pool[top[b][r], :] : 0.
// grid (100 r, 8 b), 192 threads x float4 = 768 floats. Fully coalesced.
__global__ __launch_bounds__(192) void gather_k(
    const float* __restrict__ pool, const int* __restrict__ topw,
    const int* __restrict__ kkw, float* __restrict__ out)
{
    int r = blockIdx.x, b = blockIdx.y, t = threadIdx.x;
    int idx = topw[b * 100 + r];
    bool keep = r < kkw[b];
    const float4* src = (const float4*)(pool + (size_t)idx * 768);
    float4* dst = (float4*)(out + (size_t)b * 76800 + (size_t)r * 768);
    float4 z = {0.f, 0.f, 0.f, 0.f};
    dst[t] = keep ? src[t] : z;
}

// ---------------------------------------------------------------------------
extern "C" void kernel_launch(void* const* d_in, const int* in_sizes, int n_in,
                              void* d_out, int out_size, void* d_ws, size_t ws_size,
                              hipStream_t stream) {
    (void)in_sizes; (void)n_in; (void)out_size; (void)ws_size;
    const float* tf    = (const float*)d_in[0];
    const float* pool  = (const float*)d_in[1];
    const float* clsT  = (const float*)d_in[2];
    const float* Wq    = (const float*)d_in[3];
    const float* bq    = (const float*)d_in[4];
    const float* Wk    = (const float*)d_in[5];
    const float* bk    = (const float*)d_in[6];
    const float* Wv    = (const float*)d_in[7];
    const float* bv    = (const float*)d_in[8];
    const float* Wo    = (const float*)d_in[9];
    const float* bo    = (const float*)d_in[10];
    const float* ln1a  = (const float*)d_in[11];
    const float* ln1b  = (const float*)d_in[12];
    const float* ln2a  = (const float*)d_in[13];
    const float* ln2b  = (const float*)d_in[14];
    const float* W1    = (const float*)d_in[15];
    const float* b1    = (const float*)d_in[16];
    const float* W2    = (const float*)d_in[17];
    const float* b2    = (const float*)d_in[18];
    const float* lnfa  = (const float*)d_in[19];
    const float* lnfb  = (const float*)d_in[20];
    const float* Wpool = (const float*)d_in[21];
    const float* bpool = (const float*)d_in[22];
    const float* Wcls  = (const float*)d_in[23];
    const float* bcls  = (const float*)d_in[24];
    float* out = (float*)d_out;
    char* ws = (char*)d_ws;

    float*  sc    = (float*)(ws + 0);          // 524,288 B (128 x 1024)
    float*  p     = (float*)(ws + 524288);     // 524,288
    float2* stats = (float2*)(ws + 1048576);   // 65,536
    float*  wkqc  = (float*)(ws + 1114112);    // 49,408 (12288 + 16, padded)
    float*  q0    = (float*)(ws + 1163520);    // 3,072
    float*  upart = (float*)(ws + 1166592);    // 6,291,456 (8 x 16 x 16 x 768)
    float*  o0    = (float*)(ws + 7458048);    // 24,576
    float*  x2w   = (float*)(ws + 7482624);    // 24,576
    float*  f1w   = (float*)(ws + 7507200);    // 98,304
    float*  x3w   = (float*)(ws + 7605504);    // 24,576
    int*    topw  = (int*)(ws + 7630080);      // 3,200
    int*    kkw   = (int*)(ws + 7633280);      // 32
    double* lp    = (double*)(ws + 7633312);   // 57,344 (8 x 8 x 112 doubles)

    q0_gemv<<<12, 256, 0, stream>>>(clsT, ln1a, ln1b, Wq, bq, q0);
    wkq_prep<<<48, 256, 0, stream>>>(Wk, bk, q0, wkqc);
    ln_scores<<<512, 256, 0, stream>>>(tf, clsT, ln1a, ln1b, wkqc, sc, stats);
    softmax_k<<<128, 256, 0, stream>>>(sc, p);
    upart_k<<<128, 256, 0, stream>>>(tf, clsT, stats, ln1a, ln1b, p, upart);
    o0_k<<<dim3(16, 8), 256, 0, stream>>>(upart, Wv, bv, o0);
    x2_k<<<dim3(12, 8), 256, 0, stream>>>(o0, Wo, bo, clsT, x2w);
    f1_k<<<dim3(24, 8), 256, 0, stream>>>(x2w, ln2a, ln2b, W1, b1, f1w);
    x3_k<<<dim3(12, 8), 256, 0, stream>>>(f1w, W2, b2, x2w, x3w);
    logits_part<<<dim3(8, 8), 256, 0, stream>>>(x3w, lnfa, lnfb, Wpool, Wcls, lp);
    head_decide<<<8, 128, 0, stream>>>(lp, bpool, bcls, out, topw, kkw);
    gather_k<<<dim3(100, 8), 192, 0, stream>>>(pool, topw, kkw, out);
}

// Round 6
// 111.037 us; speedup vs baseline: 3.8778x; 1.2268x over previous
//
#include <hip/hip_runtime.h>

// ---------------------------------------------------------------------------
// PromptSelector — collapsed-algebra version.
// Outputs depend only on the CLS row. K/V GEMMs are algebraically folded:
//   scores[b,h,j] = rden_j*(dot(ga*x_j, wk[:,h]) - mean_j*Sgw[h]) + CgbC[h]
// (LN expanded algebraically: Sgw = sum ga*wk, CgbC = sum gb*wk + bias-dot)
//   o[b,h,:]      = (sum_j p_j Xln[b,j,:]) @ Wv_h + bv_h
// Round 6: ln_scores rewritten — wk in 48 regs/thread (no 52KB LDS table),
// raw-moment LN (s1,s2) so only 2 barriers/row, 1024 blocks. upart_k widened
// to 256 blocks with prefetch. Head decisions in double as before.
// ---------------------------------------------------------------------------

#define OUT_CLS_OFF 614400   // 8*100*768

// block-wide (256 thr) sum reduce; red must hold >=4 floats
__device__ __forceinline__ float bsum256(float v, float* red) {
    int lane = threadIdx.x & 63, w = threadIdx.x >> 6;
#pragma unroll
    for (int off = 1; off < 64; off <<= 1) v += __shfl_xor(v, off);
    __syncthreads();
    if (lane == 0) red[w] = v;
    __syncthreads();
    return red[0] + red[1] + red[2] + red[3];
}
__device__ __forceinline__ float bmax256(float v, float* red) {
    int lane = threadIdx.x & 63, w = threadIdx.x >> 6;
#pragma unroll
    for (int off = 1; off < 64; off <<= 1) v = fmaxf(v, __shfl_xor(v, off));
    __syncthreads();
    if (lane == 0) red[w] = v;
    __syncthreads();
    return fmaxf(fmaxf(red[0], red[1]), fmaxf(red[2], red[3]));
}

// ---------------------------------------------------------------------------
// q0 = LN1(cls) @ Wq + bq, LN fused. grid 12, block 256.
__global__ __launch_bounds__(256) void q0_gemv(
    const float* __restrict__ clsT, const float* __restrict__ ga,
    const float* __restrict__ gb, const float* __restrict__ Wq,
    const float* __restrict__ bq, float* __restrict__ q0)
{
    __shared__ float ys[768];
    __shared__ float red[4];
    __shared__ float4 part[16][17];
    int t = threadIdx.x;
    float a0 = clsT[t], a1 = clsT[t + 256], a2 = clsT[t + 512];
    float mean = bsum256(a0 + a1 + a2, red) * (1.0f / 768.0f);
    float d0 = a0 - mean, d1 = a1 - mean, d2 = a2 - mean;
    float var = bsum256(d0 * d0 + d1 * d1 + d2 * d2, red) * (1.0f / 767.0f);
    float den = sqrtf(var) + 1e-6f;
    ys[t]       = (ga[t] * d0) / den + gb[t];
    ys[t + 256] = (ga[t + 256] * d1) / den + gb[t + 256];
    ys[t + 512] = (ga[t + 512] * d2) / den + gb[t + 512];
    __syncthreads();
    int c = blockIdx.x * 64 + (t & 15) * 4;
    int kq = t >> 4;
    float4 acc = {0.f, 0.f, 0.f, 0.f};
#pragma unroll 8
    for (int i = 0; i < 48; ++i) {
        int k = kq * 48 + i;
        float4 w = *(const float4*)&Wq[(size_t)k * 768 + c];
        float y = ys[k];
        acc.x = fmaf(y, w.x, acc.x); acc.y = fmaf(y, w.y, acc.y);
        acc.z = fmaf(y, w.z, acc.z); acc.w = fmaf(y, w.w, acc.w);
    }
    part[kq][t & 15] = acc;
    __syncthreads();
    if (t < 16) {
        float4 s = {0.f, 0.f, 0.f, 0.f};
#pragma unroll
        for (int i = 0; i < 16; ++i) {
            float4 v = part[i][t];
            s.x += v.x; s.y += v.y; s.z += v.z; s.w += v.w;
        }
        int cc = blockIdx.x * 64 + t * 4;
        float4 b4 = *(const float4*)&bq[cc];
        q0[cc] = s.x + b4.x; q0[cc + 1] = s.y + b4.y;
        q0[cc + 2] = s.z + b4.z; q0[cc + 3] = s.w + b4.w;
    }
}

// ---------------------------------------------------------------------------
// wkq[k][h] = (Wk[k, h*48..+48] . q0[h*48..+48]) / sqrt(48); +16 bias terms.
// grid 48 x 256.
__global__ __launch_bounds__(256) void wkq_prep(
    const float* __restrict__ Wk, const float* __restrict__ bk,
    const float* __restrict__ q0, float* __restrict__ wkqc)
{
    __shared__ float qs[768];
    int t = threadIdx.x;
    qs[t] = q0[t]; qs[t + 256] = q0[t + 256]; qs[t + 512] = q0[t + 512];
    __syncthreads();
    const float invs = 0.14433756729740643f;  // 1/sqrt(48)
    int kl = t >> 4, h = t & 15;
    int k = blockIdx.x * 16 + kl;
    const float* wr = Wk + (size_t)k * 768 + h * 48;
    const float* qh = qs + h * 48;
    float a = 0.f;
#pragma unroll
    for (int d = 0; d < 48; d += 4) {
        float4 w = *(const float4*)&wr[d];
        a += w.x * qh[d] + w.y * qh[d + 1] + w.z * qh[d + 2] + w.w * qh[d + 3];
    }
    wkqc[k * 16 + h] = a * invs;
    if (blockIdx.x == 0 && t < 16) {
        float c = 0.f;
        for (int d = 0; d < 48; ++d) c += bk[t * 48 + d] * qs[t * 48 + d];
        wkqc[12288 + t] = c * invs;
    }
}

// ---------------------------------------------------------------------------
// Per-head LN-expansion constants: Sgw[h] = sum_d ga[d]*wk[d][h] at 12304,
// CgbC[h] = sum_d gb[d]*wk[d][h] + c16[h] at 12320. Single block.
__global__ __launch_bounds__(256) void wkq_consts(
    const float* __restrict__ ga, const float* __restrict__ gb,
    float* __restrict__ wkqc)
{
    __shared__ float pA[16][17], pB[16][17];
    int t = threadIdx.x;
    int h = t & 15, dg = t >> 4;
    float a = 0.f, bs = 0.f;
#pragma unroll 8
    for (int i = 0; i < 48; ++i) {
        int d = dg * 48 + i;
        float wv = wkqc[d * 16 + h];
        a = fmaf(ga[d], wv, a);
        bs = fmaf(gb[d], wv, bs);
    }
    pA[dg][h] = a; pB[dg][h] = bs;
    __syncthreads();
    if (t < 16) {
        float sa = 0.f, sb = 0.f;
#pragma unroll
        for (int i = 0; i < 16; ++i) { sa += pA[i][t]; sb += pB[i][t]; }
        wkqc[12304 + t] = sa;
        wkqc[12320 + t] = sb + wkqc[12288 + t];
    }
}

// ---------------------------------------------------------------------------
// Pass 1: scores for all 8192 rows via raw moments + register-held wk.
// grid 1024 (8 rows/block). Per row: 2 barriers. Saves (mean, rden) / row.
__global__ __launch_bounds__(256) void ln_scores(
    const float* __restrict__ tf, const float* __restrict__ clsT,
    const float* __restrict__ ga, const float* __restrict__ wkqc,
    float* __restrict__ sc, float2* __restrict__ stats)
{
    __shared__ float tr[256][17];      // padded transpose buffer (17.4 KB)
    __shared__ float partw[4][16];
    __shared__ float red[2][4][2];     // s1,s2 per wave, row-parity dbuf
    int t = threadIdx.x;
    int l = t & 63, w = t >> 6;

    // 48 wk registers: rows t, t+256, t+512 (16 heads each)
    float wk0[16], wk1[16], wk2[16];
    {
        const float4* p0 = (const float4*)(wkqc + t * 16);
        const float4* p1 = (const float4*)(wkqc + (t + 256) * 16);
        const float4* p2 = (const float4*)(wkqc + (t + 512) * 16);
#pragma unroll
        for (int q = 0; q < 4; ++q) {
            float4 v0 = p0[q], v1 = p1[q], v2 = p2[q];
            wk0[q * 4] = v0.x; wk0[q * 4 + 1] = v0.y; wk0[q * 4 + 2] = v0.z; wk0[q * 4 + 3] = v0.w;
            wk1[q * 4] = v1.x; wk1[q * 4 + 1] = v1.y; wk1[q * 4 + 2] = v1.z; wk1[q * 4 + 3] = v1.w;
            wk2[q * 4] = v2.x; wk2[q * 4 + 1] = v2.y; wk2[q * 4 + 2] = v2.z; wk2[q * 4 + 3] = v2.w;
        }
    }
    float ga0 = ga[t], ga1 = ga[t + 256], ga2 = ga[t + 512];
    float Sg = wkqc[12304 + (t & 15)];
    float Cg = wkqc[12320 + (t & 15)];

    int r0 = blockIdx.x * 8;
    for (int r = 0; r < 8; ++r) {
        int row = r0 + r;
        int b = row >> 10, j = row & 1023;
        const float* src = j ? (tf + ((size_t)b * 1023 + (j - 1)) * 768) : clsT;
        float x0 = src[t], x1 = src[t + 256], x2 = src[t + 512];
        float s1 = x0 + x1 + x2;
        float s2 = fmaf(x0, x0, fmaf(x1, x1, x2 * x2));
        float g0 = ga0 * x0, g1 = ga1 * x1, g2 = ga2 * x2;
        float dt[16];
#pragma unroll
        for (int h = 0; h < 16; ++h)
            dt[h] = fmaf(g0, wk0[h], fmaf(g1, wk1[h], g2 * wk2[h]));
        // wave butterfly for raw moments
#pragma unroll
        for (int off = 1; off < 64; off <<= 1) {
            s1 += __shfl_xor(s1, off);
            s2 += __shfl_xor(s2, off);
        }
        if (l == 0) { red[r & 1][w][0] = s1; red[r & 1][w][1] = s2; }
#pragma unroll
        for (int h = 0; h < 16; ++h) tr[t][h] = dt[h];
        __syncthreads();                       // B1
        int hh = t & 15, ch = t >> 4;
        float v = 0.f;
#pragma unroll
        for (int i = 0; i < 16; ++i) v += tr[ch * 16 + i][hh];
        v += __shfl_xor(v, 16);
        v += __shfl_xor(v, 32);
        if (l < 16) partw[w][l] = v;
        __syncthreads();                       // B2
        if (t < 16) {
            float dtot = partw[0][t] + partw[1][t] + partw[2][t] + partw[3][t];
            float s1t = red[r & 1][0][0] + red[r & 1][1][0] + red[r & 1][2][0] + red[r & 1][3][0];
            float s2t = red[r & 1][0][1] + red[r & 1][1][1] + red[r & 1][2][1] + red[r & 1][3][1];
            float mean = s1t * (1.0f / 768.0f);
            float var = (s2t - mean * s1t) * (1.0f / 767.0f);
            float rden = 1.0f / (sqrtf(var) + 1e-6f);
            float sv = rden * (dtot - mean * Sg) + Cg;
            sc[(((size_t)b * 16 + t) << 10) + j] = sv;
            if (t == 0) stats[row] = make_float2(mean, rden);
        }
    }
}

// ---------------------------------------------------------------------------
// softmax over j (1024) per (b,h). grid 128.
__global__ __launch_bounds__(256) void softmax_k(
    const float* __restrict__ sc, float* __restrict__ p)
{
    __shared__ float red[4];
    int bh = blockIdx.x, t = threadIdx.x;
    const float4* s4 = (const float4*)(sc + ((size_t)bh << 10));
    float4 v = s4[t];
    float m = fmaxf(fmaxf(v.x, v.y), fmaxf(v.z, v.w));
    float M = bmax256(m, red);
    float e0 = expf(v.x - M), e1 = expf(v.y - M), e2 = expf(v.z - M), e3 = expf(v.w - M);
    float Z = bsum256(e0 + e1 + e2 + e3, red);
    float4 o; o.x = e0 / Z; o.y = e1 / Z; o.z = e2 / Z; o.w = e3 / Z;
    ((float4*)(p + ((size_t)bh << 10)))[t] = o;
}

// ---------------------------------------------------------------------------
// Pass 2: partial u[b,h,:] = sum_j p[b,h,j]*Xln[b,j,:] over a 32-row j-chunk.
// grid 256 = (b 8) x (jc 32). LN from saved stats; next-row prefetch.
__global__ __launch_bounds__(256) void upart_k(
    const float* __restrict__ tf, const float* __restrict__ clsT,
    const float2* __restrict__ stats, const float* __restrict__ ga,
    const float* __restrict__ gb, const float* __restrict__ p,
    float* __restrict__ up)
{
    __shared__ float ps[16][32];
    int b = blockIdx.x & 7, jc = blockIdx.x >> 3;   // jc 0..31
    int t = threadIdx.x;
    if (t < 128) {   // stage p[16][32] slice
        int h = t >> 3, j4 = (t & 7) * 4;
        const float* prow = p + (((size_t)b * 16 + h) << 10) + jc * 32 + j4;
        float4 pv = *(const float4*)prow;
        ps[h][j4] = pv.x; ps[h][j4 + 1] = pv.y; ps[h][j4 + 2] = pv.z; ps[h][j4 + 3] = pv.w;
    }
    __syncthreads();
    float ga0 = ga[t], ga1 = ga[t + 256], ga2 = ga[t + 512];
    float gb0 = gb[t], gb1 = gb[t + 256], gb2 = gb[t + 512];
    float acc[16][3];
#pragma unroll
    for (int h = 0; h < 16; ++h) { acc[h][0] = 0.f; acc[h][1] = 0.f; acc[h][2] = 0.f; }

    int j0 = jc * 32;
    const float* s0p = j0 ? (tf + ((size_t)b * 1023 + (j0 - 1)) * 768) : clsT;
    float nx0 = s0p[t], nx1 = s0p[t + 256], nx2 = s0p[t + 512];
    float2 nst = stats[(b << 10) + j0];

    for (int jj = 0; jj < 32; ++jj) {
        float x0 = nx0, x1 = nx1, x2 = nx2;
        float2 st = nst;
        if (jj < 31) {
            int j2 = j0 + jj + 1;   // >= 1 always
            const float* sp = tf + ((size_t)b * 1023 + (j2 - 1)) * 768;
            nx0 = sp[t]; nx1 = sp[t + 256]; nx2 = sp[t + 512];
            nst = stats[(b << 10) + j2];
        }
        float xl0 = (ga0 * (x0 - st.x)) * st.y + gb0;
        float xl1 = (ga1 * (x1 - st.x)) * st.y + gb1;
        float xl2 = (ga2 * (x2 - st.x)) * st.y + gb2;
#pragma unroll
        for (int h = 0; h < 16; ++h) {
            float ph = ps[h][jj];
            acc[h][0] = fmaf(ph, xl0, acc[h][0]);
            acc[h][1] = fmaf(ph, xl1, acc[h][1]);
            acc[h][2] = fmaf(ph, xl2, acc[h][2]);
        }
    }
    float* o = up + (((size_t)b * 32 + jc) * 16) * 768;
#pragma unroll
    for (int h = 0; h < 16; ++h) {
        o[h * 768 + t] = acc[h][0];
        o[h * 768 + t + 256] = acc[h][1];
        o[h * 768 + t + 512] = acc[h][2];
    }
}

// ---------------------------------------------------------------------------
// reduce 32 u-partials, then o0 head-slice = u @ Wv[:,h*48..+48] + bv.
// grid (16 h, 8 b).
__global__ __launch_bounds__(256) void o0_k(
    const float* __restrict__ up, const float* __restrict__ Wv,
    const float* __restrict__ bv, float* __restrict__ o0)
{
    __shared__ float us[768];
    __shared__ float part[4][64];
    int h = blockIdx.x, b = blockIdx.y, t = threadIdx.x;
    float s0 = 0.f, s1 = 0.f, s2 = 0.f;
#pragma unroll 8
    for (int jc = 0; jc < 32; ++jc) {
        const float* q = up + (((size_t)b * 32 + jc) * 16 + h) * 768;
        s0 += q[t]; s1 += q[t + 256]; s2 += q[t + 512];
    }
    us[t] = s0; us[t + 256] = s1; us[t + 512] = s2;
    __syncthreads();
    int dd = t & 63, kg = t >> 6;    // 4 groups x 192 k
    float a = 0.f;
    if (dd < 48) {
#pragma unroll 8
        for (int i = 0; i < 192; ++i) {
            int k = kg * 192 + i;
            a = fmaf(us[k], Wv[(size_t)k * 768 + h * 48 + dd], a);
        }
    }
    part[kg][dd] = a;
    __syncthreads();
    if (t < 48)
        o0[(size_t)b * 768 + h * 48 + t] =
            part[0][t] + part[1][t] + part[2][t] + part[3][t] + bv[h * 48 + t];
}

// ---------------------------------------------------------------------------
// x2 = clsT + o0 @ Wo + bo. grid (12, 8).
__global__ __launch_bounds__(256) void x2_k(
    const float* __restrict__ o0, const float* __restrict__ Wo,
    const float* __restrict__ bo, const float* __restrict__ clsT,
    float* __restrict__ x2w)
{
    __shared__ float ys[768];
    __shared__ float4 part[16][17];
    int b = blockIdx.y, t = threadIdx.x;
    const float* xr = o0 + (size_t)b * 768;
    ys[t] = xr[t]; ys[t + 256] = xr[t + 256]; ys[t + 512] = xr[t + 512];
    __syncthreads();
    int c = blockIdx.x * 64 + (t & 15) * 4;
    int kq = t >> 4;
    float4 acc = {0.f, 0.f, 0.f, 0.f};
#pragma unroll 8
    for (int i = 0; i < 48; ++i) {
        int k = kq * 48 + i;
        float4 w = *(const float4*)&Wo[(size_t)k * 768 + c];
        float y = ys[k];
        acc.x = fmaf(y, w.x, acc.x); acc.y = fmaf(y, w.y, acc.y);
        acc.z = fmaf(y, w.z, acc.z); acc.w = fmaf(y, w.w, acc.w);
    }
    part[kq][t & 15] = acc;
    __syncthreads();
    if (t < 16) {
        float4 s = {0.f, 0.f, 0.f, 0.f};
#pragma unroll
        for (int i = 0; i < 16; ++i) {
            float4 v = part[i][t];
            s.x += v.x; s.y += v.y; s.z += v.z; s.w += v.w;
        }
        int cc = blockIdx.x * 64 + t * 4;
        float4 b4 = *(const float4*)&bo[cc];
        float4 r4 = *(const float4*)&clsT[cc];
        float* o = x2w + (size_t)b * 768 + cc;
        o[0] = s.x + b4.x + r4.x; o[1] = s.y + b4.y + r4.y;
        o[2] = s.z + b4.z + r4.z; o[3] = s.w + b4.w + r4.w;
    }
}

// ---------------------------------------------------------------------------
// f1 = relu(LN2(x2) @ W1 + b1), LN fused. grid (24, 8).
__global__ __launch_bounds__(256) void f1_k(
    const float* __restrict__ x2w, const float* __restrict__ ga,
    const float* __restrict__ gb, const float* __restrict__ W1,
    const float* __restrict__ b1, float* __restrict__ f1w)
{
    __shared__ float ys[768];
    __shared__ float red[4];
    __shared__ float4 part[8][33];
    int b = blockIdx.y, t = threadIdx.x;
    const float* xr = x2w + (size_t)b * 768;
    float a0 = xr[t], a1 = xr[t + 256], a2 = xr[t + 512];
    float mean = bsum256(a0 + a1 + a2, red) * (1.0f / 768.0f);
    float d0 = a0 - mean, d1 = a1 - mean, d2 = a2 - mean;
    float var = bsum256(d0 * d0 + d1 * d1 + d2 * d2, red) * (1.0f / 767.0f);
    float den = sqrtf(var) + 1e-6f;
    ys[t]       = (ga[t] * d0) / den + gb[t];
    ys[t + 256] = (ga[t + 256] * d1) / den + gb[t + 256];
    ys[t + 512] = (ga[t + 512] * d2) / den + gb[t + 512];
    __syncthreads();
    int c = blockIdx.x * 128 + (t & 31) * 4;
    int kq = t >> 5;
    float4 acc = {0.f, 0.f, 0.f, 0.f};
#pragma unroll 8
    for (int i = 0; i < 96; ++i) {
        int k = kq * 96 + i;
        float4 w = *(const float4*)&W1[(size_t)k * 3072 + c];
        float y = ys[k];
        acc.x = fmaf(y, w.x, acc.x); acc.y = fmaf(y, w.y, acc.y);
        acc.z = fmaf(y, w.z, acc.z); acc.w = fmaf(y, w.w, acc.w);
    }
    part[kq][t & 31] = acc;
    __syncthreads();
    if (t < 32) {
        float4 s = {0.f, 0.f, 0.f, 0.f};
#pragma unroll
        for (int i = 0; i < 8; ++i) {
            float4 v = part[i][t];
            s.x += v.x; s.y += v.y; s.z += v.z; s.w += v.w;
        }
        int cc = blockIdx.x * 128 + t * 4;
        float4 b4 = *(const float4*)&b1[cc];
        float* o = f1w + (size_t)b * 3072 + cc;
        o[0] = fmaxf(s.x + b4.x, 0.f); o[1] = fmaxf(s.y + b4.y, 0.f);
        o[2] = fmaxf(s.z + b4.z, 0.f); o[3] = fmaxf(s.w + b4.w, 0.f);
    }
}

// ---------------------------------------------------------------------------
// x3 = x2 + f1 @ W2 + b2. grid (12, 8).
__global__ __launch_bounds__(256) void x3_k(
    const float* __restrict__ f1w, const float* __restrict__ W2,
    const float* __restrict__ b2, const float* __restrict__ x2w,
    float* __restrict__ x3w)
{
    __shared__ float ys[3072];
    __shared__ float4 part[16][17];
    int b = blockIdx.y, t = threadIdx.x;
    const float* xr = f1w + (size_t)b * 3072;
    for (int i = t; i < 3072; i += 256) ys[i] = xr[i];
    __syncthreads();
    int c = blockIdx.x * 64 + (t & 15) * 4;
    int kq = t >> 4;
    float4 acc = {0.f, 0.f, 0.f, 0.f};
#pragma unroll 8
    for (int i = 0; i < 192; ++i) {
        int k = kq * 192 + i;
        float4 w = *(const float4*)&W2[(size_t)k * 768 + c];
        float y = ys[k];
        acc.x = fmaf(y, w.x, acc.x); acc.y = fmaf(y, w.y, acc.y);
        acc.z = fmaf(y, w.z, acc.z); acc.w = fmaf(y, w.w, acc.w);
    }
    part[kq][t & 15] = acc;
    __syncthreads();
    if (t < 16) {
        float4 s = {0.f, 0.f, 0.f, 0.f};
#pragma unroll
        for (int i = 0; i < 16; ++i) {
            float4 v = part[i][t];
            s.x += v.x; s.y += v.y; s.z += v.z; s.w += v.w;
        }
        int cc = blockIdx.x * 64 + t * 4;
        float4 b4 = *(const float4*)&b2[cc];
        const float* x2r = x2w + (size_t)b * 768 + cc;
        float* o = x3w + (size_t)b * 768 + cc;
        o[0] = x2r[0] + s.x + b4.x; o[1] = x2r[1] + s.y + b4.y;
        o[2] = x2r[2] + s.z + b4.z; o[3] = x2r[3] + s.w + b4.w;
    }
}

// ---------------------------------------------------------------------------
// Head logits, k-split: block (kg, b) computes double partials over k-chunk
// kg*96..+96 for 100 pool cols + 7 class cols. LNf fused. lp[b][kg][112].
__global__ __launch_bounds__(256) void logits_part(
    const float* __restrict__ x3w, const float* __restrict__ ga,
    const float* __restrict__ gb, const float* __restrict__ Wpool,
    const float* __restrict__ Wcls, double* __restrict__ lp)
{
    __shared__ float ys[768];
    __shared__ float red[4];
    int kg = blockIdx.x, b = blockIdx.y, t = threadIdx.x;
    const float* xr = x3w + (size_t)b * 768;
    float a0 = xr[t], a1 = xr[t + 256], a2 = xr[t + 512];
    float mean = bsum256(a0 + a1 + a2, red) * (1.0f / 768.0f);
    float d0 = a0 - mean, d1 = a1 - mean, d2 = a2 - mean;
    float var = bsum256(d0 * d0 + d1 * d1 + d2 * d2, red) * (1.0f / 767.0f);
    float den = sqrtf(var) + 1e-6f;
    ys[t]       = (ga[t] * d0) / den + gb[t];
    ys[t + 256] = (ga[t + 256] * d1) / den + gb[t + 256];
    ys[t + 512] = (ga[t + 512] * d2) / den + gb[t + 512];
    __syncthreads();
    int kbase = kg * 96;
    if (t < 100) {
        double a = 0.0;
#pragma unroll 8
        for (int i = 0; i < 96; ++i) {
            int k = kbase + i;
            a = fma((double)ys[k], (double)Wpool[k * 100 + t], a);
        }
        lp[((size_t)b * 8 + kg) * 112 + t] = a;
    } else if (t < 107) {
        int c = t - 100;
        double a = 0.0;
#pragma unroll 8
        for (int i = 0; i < 96; ++i) {
            int k = kbase + i;
            a = fma((double)ys[k], (double)Wcls[k * 7 + c], a);
        }
        lp[((size_t)b * 8 + kg) * 112 + t] = a;
    }
}

// ---------------------------------------------------------------------------
// Head decide: sum 8 partials (fixed order), pool softmax, class logits out,
// entropy -> adjusted_k, stable descending rank. grid 8, block 128, double.
__global__ __launch_bounds__(128) void head_decide(
    const double* __restrict__ lp, const float* __restrict__ bpool,
    const float* __restrict__ bcls, float* __restrict__ out,
    int* __restrict__ topw, int* __restrict__ kkw)
{
    __shared__ double sP[100];
    __shared__ double sC7[7];
    int b = blockIdx.x, t = threadIdx.x;
    if (t < 107) {
        double a = (t < 100) ? (double)bpool[t] : (double)bcls[t - 100];
#pragma unroll
        for (int kg = 0; kg < 8; ++kg) a += lp[((size_t)b * 8 + kg) * 112 + t];
        if (t < 100) sP[t] = a;
        else {
            sC7[t - 100] = a;
            out[OUT_CLS_OFF + b * 7 + (t - 100)] = (float)a;
        }
    }
    __syncthreads();
    double mx = sP[0];
    for (int j = 1; j < 100; ++j) mx = fmax(mx, sP[j]);
    double e = (t < 100) ? exp(sP[t] - mx) : 0.0;
    __syncthreads();
    if (t < 100) sP[t] = e;
    __syncthreads();
    double zs = 0.0;
    for (int j = 0; j < 100; ++j) zs += sP[j];
    __syncthreads();
    if (t < 100) sP[t] = e / zs;
    __syncthreads();
    if (t == 0) {
        double m7 = sC7[0];
        for (int j = 1; j < 7; ++j) m7 = fmax(m7, sC7[j]);
        double es[7]; double z = 0.0;
        for (int j = 0; j < 7; ++j) { es[j] = exp(sC7[j] - m7); z += es[j]; }
        double ent = 0.0;
        for (int j = 0; j < 7; ++j) { double pr = es[j] / z; ent -= pr * log(pr + 1e-9); }
        double ne = ent / log(7.0);
        int kk = (int)floor(1.0 + ne * 99.0);
        kkw[b] = kk < 1 ? 1 : (kk > 100 ? 100 : kk);
    }
    if (t < 100) {
        double pi = sP[t];
        int r = 0;
        for (int j = 0; j < 100; ++j) {
            double pj = sP[j];
            r += (pj > pi) || (pj == pi && j < t);
        }
        topw[b * 100 + r] = t;   // descending, stable (lower index first)
    }
}

// ---------------------------------------------------------------------------
// gather: out[b, r, :] = (r < kk[b]) ? pool[top[b][r], :] : 0.
// grid (100 r, 8 b), 192 threads x float4. Fully coalesced.
__global__ __launch_bounds__(192) void gather_k(
    const float* __restrict__ pool, const int* __restrict__ topw,
    const int* __restrict__ kkw, float* __restrict__ out)
{
    int r = blockIdx.x, b = blockIdx.y, t = threadIdx.x;
    int idx = topw[b * 100 + r];
    bool keep = r < kkw[b];
    const float4* src = (const float4*)(pool + (size_t)idx * 768);
    float4* dst = (float4*)(out + (size_t)b * 76800 + (size_t)r * 768);
    float4 z = {0.f, 0.f, 0.f, 0.f};
    dst[t] = keep ? src[t] : z;
}

// ---------------------------------------------------------------------------
extern "C" void kernel_launch(void* const* d_in, const int* in_sizes, int n_in,
                              void* d_out, int out_size, void* d_ws, size_t ws_size,
                              hipStream_t stream) {
    (void)in_sizes; (void)n_in; (void)out_size; (void)ws_size;
    const float* tf    = (const float*)d_in[0];
    const float* pool  = (const float*)d_in[1];
    const float* clsT  = (const float*)d_in[2];
    const float* Wq    = (const float*)d_in[3];
    const float* bq    = (const float*)d_in[4];
    const float* Wk    = (const float*)d_in[5];
    const float* bk    = (const float*)d_in[6];
    const float* Wv    = (const float*)d_in[7];
    const float* bv    = (const float*)d_in[8];
    const float* Wo    = (const float*)d_in[9];
    const float* bo    = (const float*)d_in[10];
    const float* ln1a  = (const float*)d_in[11];
    const float* ln1b  = (const float*)d_in[12];
    const float* ln2a  = (const float*)d_in[13];
    const float* ln2b  = (const float*)d_in[14];
    const float* W1    = (const float*)d_in[15];
    const float* b1    = (const float*)d_in[16];
    const float* W2    = (const float*)d_in[17];
    const float* b2    = (const float*)d_in[18];
    const float* lnfa  = (const float*)d_in[19];
    const float* lnfb  = (const float*)d_in[20];
    const float* Wpool = (const float*)d_in[21];
    const float* bpool = (const float*)d_in[22];
    const float* Wcls  = (const float*)d_in[23];
    const float* bcls  = (const float*)d_in[24];
    float* out = (float*)d_out;
    char* ws = (char*)d_ws;

    float*  sc    = (float*)(ws + 0);           // 524,288 B (128 x 1024)
    float*  p     = (float*)(ws + 524288);      // 524,288
    float2* stats = (float2*)(ws + 1048576);    // 65,536
    float*  wkqc  = (float*)(ws + 1114112);     // 49,408 (12288+16+16+16)
    float*  q0    = (float*)(ws + 1163520);     // 3,072
    float*  upart = (float*)(ws + 1166592);     // 12,582,912 (8 x 32 x 16 x 768)
    float*  o0    = (float*)(ws + 13749504);    // 24,576
    float*  x2w   = (float*)(ws + 13774080);    // 24,576
    float*  f1w   = (float*)(ws + 13798656);    // 98,304
    float*  x3w   = (float*)(ws + 13896960);    // 24,576
    int*    topw  = (int*)(ws + 13921536);      // 3,200
    int*    kkw   = (int*)(ws + 13924736);      // 32
    double* lp    = (double*)(ws + 13924768);   // 57,344 (8 x 8 x 112 doubles)

    q0_gemv<<<12, 256, 0, stream>>>(clsT, ln1a, ln1b, Wq, bq, q0);
    wkq_prep<<<48, 256, 0, stream>>>(Wk, bk, q0, wkqc);
    wkq_consts<<<1, 256, 0, stream>>>(ln1a, ln1b, wkqc);
    ln_scores<<<1024, 256, 0, stream>>>(tf, clsT, ln1a, wkqc, sc, stats);
    softmax_k<<<128, 256, 0, stream>>>(sc, p);
    upart_k<<<256, 256, 0, stream>>>(tf, clsT, stats, ln1a, ln1b, p, upart);
    o0_k<<<dim3(16, 8), 256, 0, stream>>>(upart, Wv, bv, o0);
    x2_k<<<dim3(12, 8), 256, 0, stream>>>(o0, Wo, bo, clsT, x2w);
    f1_k<<<dim3(24, 8), 256, 0, stream>>>(x2w, ln2a, ln2b, W1, b1, f1w);
    x3_k<<<dim3(12, 8), 256, 0, stream>>>(f1w, W2, b2, x2w, x3w);
    logits_part<<<dim3(8, 8), 256, 0, stream>>>(x3w, lnfa, lnfb, Wpool, Wcls, lp);
    head_decide<<<8, 128, 0, stream>>>(lp, bpool, bcls, out, topw, kkw);
    gather_k<<<dim3(100, 8), 192, 0, stream>>>(pool, topw, kkw, out);
}